// Round 8
// baseline (359.257 us; speedup 1.0000x reference)
//
#include <hip/hip_runtime.h>
#include <hip/hip_bf16.h>

#define BB 8
#define CC 512
#define HO 64
#define HP 66
#define NPIX (BB*HO*HO)   // 32768

typedef float f32x4 __attribute__((ext_vector_type(4)));
typedef __bf16 bf16x8 __attribute__((ext_vector_type(8)));
using bf16 = __hip_bfloat16;

__device__ __forceinline__ void gload16(const void* g, void* l) {
    __builtin_amdgcn_global_load_lds((const __attribute__((address_space(1))) void*)g,
                                     (__attribute__((address_space(3))) void*)l, 16, 0, 0);
}

__device__ __forceinline__ float waveRedSum(float v) {
    #pragma unroll
    for (int off = 32; off; off >>= 1) v += __shfl_down(v, off);
    return v;
}

// thread t -> (i = t&511, o = t>>9). Reads W[i][o][0..8] (contiguous 36B),
// writes S2ho[o][i] = he^2 * sum W^2, and keffT[tap][o][i] = he*W[i][o][8-tap].
__global__ void prep_weights(const float* __restrict__ Wsrc, float* __restrict__ S2ho,
                             bf16* __restrict__ keffT, float he) {
    int t = blockIdx.x * blockDim.x + threadIdx.x;
    int i = t & (CC-1), o = t >> 9;
    const float* wp = Wsrc + (i*CC + o)*9;
    float v[9]; float s2 = 0.f;
    #pragma unroll
    for (int k = 0; k < 9; ++k) { v[k] = wp[k] * he; s2 += v[k]*v[k]; }
    S2ho[o*CC + i] = s2;
    #pragma unroll
    for (int tp = 0; tp < 9; ++tp) keffT[(tp*CC + o)*CC + i] = (bf16)v[8 - tp];
}

// one wave per (set, b, i): style[b,i] = sum_d w[b,d]*A[i,d]/sqrt(512) + Ab[i]
__global__ void style_kernel(const float* __restrict__ w,
                             const float* __restrict__ A1, const float* __restrict__ A1b,
                             const float* __restrict__ A2, const float* __restrict__ A2b,
                             float* __restrict__ s1, float* __restrict__ s2) {
    int wid = (blockIdx.x * blockDim.x + threadIdx.x) >> 6;
    int lane = threadIdx.x & 63;
    int set = wid >= BB*CC; int rem = set ? wid - BB*CC : wid;
    int b = rem >> 9, i = rem & (CC-1);
    const float* A = set ? A2 : A1;
    const float* wb = w + b*CC;
    float sum = 0.f;
    for (int d = lane; d < CC; d += 64) sum += wb[d] * A[i*CC + d];
    sum = waveRedSum(sum);
    if (lane == 0) {
        float r = sum * 0.04419417382415922f + (set ? A2b : A1b)[i];
        (set ? s2 : s1)[b*CC + i] = r;
    }
}

// one wave per (set, b, o): dg = gain * rsqrt(sum_i style^2 * S2ho[o][i] + eps)
__global__ void demod_kernel(const float* __restrict__ s1, const float* __restrict__ S21,
                             const float* __restrict__ s2, const float* __restrict__ S22,
                             float* __restrict__ dg1, float* __restrict__ dg2, float gain) {
    int wid = (blockIdx.x * blockDim.x + threadIdx.x) >> 6;
    int lane = threadIdx.x & 63;
    int set = wid >= BB*CC; int rem = set ? wid - BB*CC : wid;
    int b = rem >> 9, o = rem & (CC-1);
    const float* st = (set ? s2 : s1) + b*CC;
    const float* S2 = (set ? S22 : S21) + o*CC;
    float sum = 0.f;
    for (int i = lane; i < CC; i += 64) { float sv = st[i]; sum += sv*sv*S2[i]; }
    sum = waveRedSum(sum);
    if (lane == 0) (set ? dg2 : dg1)[b*CC + o] = gain * rsqrtf(sum + 1e-8f);
}

// block = (b, p, q-group of 4), 512 threads = channels.
__global__ void upsample_mod(const float* __restrict__ x, const float* __restrict__ s1,
                             bf16* __restrict__ xs1) {
    __shared__ float usl[16][CC];
    int blk = blockIdx.x;
    int i = threadIdx.x;
    int b = blk >> 10, rem = blk & 1023, p = rem >> 4, q0 = (rem & 15) << 2;
    const float scale = 31.0f / 63.0f;
    float chf = p * scale; int h0 = (int)chf; float fh = chf - h0; int h1 = min(h0 + 1, 31);
    int wa = min(((int)(q0 * scale)) & ~3, 24);    // 4-aligned, wa+7 <= 31
    const float* xb = x + ((size_t)(b*CC + i) << 10);
    f32x4 r00 = *(const f32x4*)(xb + (h0 << 5) + wa);
    f32x4 r01 = *(const f32x4*)(xb + (h0 << 5) + wa + 4);
    f32x4 r10 = *(const f32x4*)(xb + (h1 << 5) + wa);
    f32x4 r11 = *(const f32x4*)(xb + (h1 << 5) + wa + 4);
    #pragma unroll
    for (int k = 0; k < 4; ++k) {
        usl[k][i] = r00[k]; usl[4 + k][i] = r01[k];
        usl[8 + k][i] = r10[k]; usl[12 + k][i] = r11[k];
    }
    float sv = s1[b*CC + i];
    #pragma unroll
    for (int dq = 0; dq < 4; ++dq) {
        int q = q0 + dq;
        float cwf = q * scale; int w0 = (int)cwf; float fw = cwf - w0;
        int i0 = w0 - wa, i1 = min(w0 + 1, 31) - wa;
        float v00 = usl[i0][i], v01 = usl[i1][i];
        float v10 = usl[8 + i0][i], v11 = usl[8 + i1][i];
        float va = v00*(1.f-fh) + v10*fh;
        float vb = v01*(1.f-fh) + v11*fh;
        float v  = (va*(1.f-fw) + vb*fw) * sv;
        xs1[(((b*HP) + p + 1)*HP + (q + 1))*CC + i] = (bf16)v;
    }
}

// zero only the 1-pixel halo ring of xs1/xs2 (replaces 2x 35.7MB memset).
__global__ void halo_zero(bf16* __restrict__ xs1, bf16* __restrict__ xs2) {
    int blk = blockIdx.x;
    bf16* dst = (blk & 1) ? xs2 : xs1;
    int idx = blk >> 1;                 // 0..2079
    int b = idx / 260, rm = idx - b*260;
    int p, q;
    if (rm < 66)       { p = 0;        q = rm; }
    else if (rm < 132) { p = 65;       q = rm - 66; }
    else if (rm < 196) { p = rm - 131; q = 0; }
    else               { p = rm - 195; q = 65; }
    f32x4* d4 = (f32x4*)(dst + ((size_t)((b*HP + p)*HP + q)) * CC);
    d4[threadIdx.x] = f32x4{0.f, 0.f, 0.f, 0.f};
}

// init outrgb planes with rgbb[c] (fused rgb accumulates on top via atomics).
// outrgb layout: [(b*3+c)*4096 + px]; 24 planes of 4096 f32.
__global__ void rgb_init(const float* __restrict__ rgbb, float* __restrict__ outrgb) {
    int t = blockIdx.x * blockDim.x + threadIdx.x;   // 24*1024 threads, f32x4 each
    int plane = t >> 10, c = plane - (plane/3)*3;
    float v = rgbb[c];
    *(f32x4*)(outrgb + (plane << 12) + ((t & 1023) << 2)) = f32x4{v, v, v, v};
}

// ---------------------------------------------------------------------------
// Implicit-GEMM 3x3 conv, m201-faithful 8-phase schedule (T2+T3+T4+T5).
// BM=BN=256, BK=64, 512 thr = 8 waves (2Mx4N), per-wave 128x64.
// K-loop verbatim from r3/r7 (best measured: 156 us, MfmaUtil 42%, 0 confl).
// PHASE1: operand-SWAPPED mfma (bfr,afr) -> acc[fm][fn] holds D[ch][px]
//   (valid: A/B fragment layouts are symmetric; values bit-identical).
//   Epilogue: lane owns 4 consecutive channels -> uint2 (4xbf16) stores,
//   32x8B instead of 128x2B (kills the 2x write amplification seen in r7).
// PHASE2: unswapped (pixel-contiguous f32x4 stores) + FUSED rgb: pc[c] += v *
//   rgbw[c,n]*he, shfl_xor-reduce over the 16 l15 lanes, atomicAdd into
//   outrgb (pre-initialized with rgbb by rgb_init). Replaces rgb_kernel's
//   64 MB re-read of outx.
// ---------------------------------------------------------------------------
#define SB  __builtin_amdgcn_sched_barrier(0)
#define BAR __builtin_amdgcn_s_barrier()
#define VMC(n)  asm volatile("s_waitcnt vmcnt(" #n ")" ::: "memory")
#define LGKM(n) asm volatile("s_waitcnt lgkmcnt(" #n ")" ::: "memory")

#define STAGE_A(d, h, U) do { \
    gload16((U) + aThr + (h)*(HP*1024),                 ldsA + (d)*32768 + (h)*16384); \
    gload16((U) + aThr + (h)*(HP*1024) + 2*(HP*1024),   ldsA + (d)*32768 + (h)*16384 + 8192); \
} while (0)

#define STAGE_B(d, h, U) do { \
    gload16((U) + bThr + (h)*32768,                     ldsB + (d)*32768 + (h)*16384); \
    gload16((U) + bThr + (h)*32768 + 131072,            ldsB + (d)*32768 + (h)*16384 + 8192); \
} while (0)

#define LOAD_A(d, fh) do { \
    _Pragma("unroll") \
    for (int fmq = 0; fmq < 4; ++fmq) { \
        afr[fmq][0] = *(const bf16x8*)(aRd + (d)*32768 + (fh)*16384 + fmq*2048 + swz0); \
        afr[fmq][1] = *(const bf16x8*)(aRd + (d)*32768 + (fh)*16384 + fmq*2048 + swz1); \
    } } while (0)

#define LOAD_B(d, nh) do { \
    _Pragma("unroll") \
    for (int fnq = 0; fnq < 2; ++fnq) { \
        bfr[nh][fnq][0] = *(const bf16x8*)(bRd + (d)*32768 + (nh)*16384 + fnq*2048 + swz0); \
        bfr[nh][fnq][1] = *(const bf16x8*)(bRd + (d)*32768 + (nh)*16384 + fnq*2048 + swz1); \
    } } while (0)

// PHASE==1: swapped operands -> acc holds D[ch][px]; else D[px][ch].
#define QUAD(fh, nh) do { \
    __builtin_amdgcn_s_setprio(1); \
    _Pragma("unroll") \
    for (int kc = 0; kc < 2; ++kc) \
    { _Pragma("unroll") \
      for (int fmq = 0; fmq < 4; ++fmq) \
      { _Pragma("unroll") \
        for (int fnq = 0; fnq < 2; ++fnq) { \
            if (PHASE == 1) \
                acc[(fh)*4+fmq][(nh)*2+fnq] = __builtin_amdgcn_mfma_f32_16x16x32_bf16( \
                    bfr[nh][fnq][kc], afr[fmq][kc], acc[(fh)*4+fmq][(nh)*2+fnq], 0, 0, 0); \
            else \
                acc[(fh)*4+fmq][(nh)*2+fnq] = __builtin_amdgcn_mfma_f32_16x16x32_bf16( \
                    afr[fmq][kc], bfr[nh][fnq][kc], acc[(fh)*4+fmq][(nh)*2+fnq], 0, 0, 0); \
        } } } \
    __builtin_amdgcn_s_setprio(0); } while (0)

// one K-step = 4 phases. cur/nxt are dbuf indices (compile-time).
#define PHSTEP(cur, nxt, aN1, bN1, aN2, g1, g3) do { \
    /* phase 0: Q(0,0) */ \
    LOAD_A(cur, 0); \
    LOAD_B(cur, 0); \
    if (g1) STAGE_B(nxt, 0, bN1); \
    LGKM(8); SB; BAR; LGKM(0); SB; \
    QUAD(0, 0); \
    VMC(4); SB; BAR; SB; \
    /* phase 1: Q(0,1) */ \
    LOAD_B(cur, 1); \
    if (g1) STAGE_B(nxt, 1, bN1); \
    SB; BAR; LGKM(0); SB; \
    QUAD(0, 1); \
    SB; BAR; SB; \
    /* phase 2: Q(1,1) */ \
    LOAD_A(cur, 1); \
    if (g1) STAGE_A(nxt, 1, aN1); \
    SB; BAR; LGKM(0); SB; \
    QUAD(1, 1); \
    SB; BAR; SB; \
    /* phase 3: Q(1,0) */ \
    if (g3) STAGE_A(cur, 0, aN2); \
    SB; BAR; SB; \
    QUAD(1, 0); \
    if (g3) { VMC(6); } else { VMC(0); } \
    SB; BAR; SB; \
} while (0)

template<int PHASE>
__global__ __launch_bounds__(512, 2) void conv_gemm(
    const bf16* __restrict__ xs, const bf16* __restrict__ keffT,
    const float* __restrict__ dg, const float* __restrict__ noise,
    const float* __restrict__ nsw, const float* __restrict__ nsb,
    const float* __restrict__ nbw, const float* __restrict__ nbb,
    const float* __restrict__ biasv, const float* __restrict__ stnext,
    bf16* __restrict__ outb, float* __restrict__ outf,
    const float* __restrict__ rgbwv, float* __restrict__ outrgb) {
    __shared__ __attribute__((aligned(16))) bf16 As[32768];   // 64 KB: 2 dbuf x 256x64
    __shared__ __attribute__((aligned(16))) bf16 Bs[32768];   // 64 KB
    const int tid = threadIdx.x;
    const int wave = tid >> 6, lane = tid & 63;
    // XCD swizzle: 256 wgs, %8==0 -> bijective.
    const int tileId = ((blockIdx.x & 7) << 5) + (blockIdx.x >> 3);
    const int mtile = tileId >> 1, ntile = tileId & 1;
    const int m0 = mtile << 8, n0 = ntile << 8;
    const int b  = m0 >> 12;
    const int p0 = (m0 & 4095) >> 6;
    const int wm = wave >> 2, wn = wave & 3;
    const int l15 = lane & 15;

    // staging thread constants (source pre-XOR-swizzled, dest linear)
    const int srcSwz = (((tid & 7) ^ ((tid >> 3) & 7)) << 4);
    const int aThr = ((tid >> 3) << 10) + srcSwz;
    const int bThr = (((tid >> 8) & 1) << 16) + (((tid >> 3) & 31) << 10) + srcSwz;
    char* const ldsA = (char*)As + tid*16;
    char* const ldsB = (char*)Bs + tid*16;

    // fragment read bases (row*128 + (slot ^ row&7)*16)
    const char* const aRd = (const char*)As + (((wm << 6) + l15) << 7);
    const char* const bRd = (const char*)Bs + (((wn << 5) + l15) << 7);
    const int swz0 = (((lane >> 4)    ) ^ (lane & 7)) << 4;
    const int swz1 = (((lane >> 4) | 4) ^ (lane & 7)) << 4;

    f32x4 acc[8][4];
    #pragma unroll
    for (int i_ = 0; i_ < 8; ++i_)
        #pragma unroll
        for (int j_ = 0; j_ < 4; ++j_) acc[i_][j_] = f32x4{0.f, 0.f, 0.f, 0.f};
    bf16x8 afr[4][2], bfr[2][2][2];

    // uniform staging bases per K-step st (0..71): tap t=st>>3, k0=(st&7)*64
    auto abase = [&](int st) -> const char* {
        int t = st >> 3; int dh = (t*11) >> 5; int dw = t - dh*3;
        return (const char*)xs + ((size_t)((b*HP + p0 + dh)*HP + dw) << 10) + ((st & 7) << 7);
    };
    auto bbase = [&](int st) -> const char* {
        int t = st >> 3;
        return (const char*)keffT + ((size_t)(t*CC + n0) << 10) + ((st & 7) << 7);
    };

    // prologue: stage units 0..4 in read order, leave units 2..4 in flight
    {
        const char* a0 = abase(0); const char* b0 = bbase(0); const char* a1 = abase(1);
        STAGE_A(0, 0, a0);
        STAGE_B(0, 0, b0);
        STAGE_B(0, 1, b0);
        STAGE_A(0, 1, a0);
        STAGE_A(1, 0, a1);
        VMC(6); SB; BAR; SB;
    }

    #pragma unroll 1
    for (int it = 0; it < 36; ++it) {
        const bool more = (it < 35);
        const char* aE = abase(2*it + 1); const char* bE = bbase(2*it + 1);
        const char* aO = abase(2*it + 2); const char* bO = bbase(2*it + 2);
        const char* aO2 = abase(2*it + 3);
        PHSTEP(0, 1, aE, bE, aO,  true, more);   // compute K-step 2it   (dbuf0)
        PHSTEP(1, 0, aO, bO, aO2, more, more);   // compute K-step 2it+1 (dbuf1)
    }

    if constexpr (PHASE == 1) {
        // swapped layout: acc[fm][fn] = D[ch][px];
        // px = m0 + wm*128 + fm*16 + l15; ch = n0 + wn*64 + fn*16 + (lane>>4)*4 + r
        const int chq = (lane >> 4) << 2;
        float ns8[8]; int pox[8];
        #pragma unroll
        for (int fm = 0; fm < 8; ++fm) {
            int mloc = m0 + (wm << 7) + (fm << 4) + l15;
            ns8[fm] = noise[mloc];
            int prow = (mloc & 4095) >> 6, qcol = mloc & 63;
            pox[fm] = ((b*HP + prow + 1)*HP + (qcol + 1))*CC;
        }
        #pragma unroll
        for (int fn = 0; fn < 4; ++fn) {
            const int cb = n0 + (wn << 6) + (fn << 4) + chq;   // 4 consecutive channels
            f32x4 dg4 = *(const f32x4*)(dg + b*CC + cb);
            f32x4 sw4 = *(const f32x4*)(nsw + cb);
            f32x4 sb4 = *(const f32x4*)(nsb + cb);
            f32x4 bw4 = *(const f32x4*)(nbw + cb);
            f32x4 bb4 = *(const f32x4*)(nbb + cb);
            f32x4 bi4 = *(const f32x4*)(biasv + cb);
            f32x4 st4 = *(const f32x4*)(stnext + b*CC + cb);
            #pragma unroll
            for (int fm = 0; fm < 8; ++fm) {
                float ns = ns8[fm];
                union { bf16 h[4]; uint2 u; } pk;
                #pragma unroll
                for (int r = 0; r < 4; ++r) {
                    float v = acc[fm][fn][r] * dg4[r];
                    v = v * (ns*sw4[r] + sb4[r]) + (ns*bw4[r] + bb4[r]) + bi4[r];
                    v = fmaxf(v, 0.2f*v);   // leaky relu 0.2
                    pk.h[r] = (bf16)(v * st4[r]);
                }
                *(uint2*)(outb + pox[fm] + cb) = pk.u;   // 8B: 4 bf16 channels
            }
        }
    } else {
        // unswapped: px = m0+wm*128+fm*16+(lane>>4)*4+r; ch = n0+wn*64+fn*16+l15
        const float* dgb = dg + b*CC;
        int nIdx[4]; float pdg[4], pnsw[4], pnsb[4], pnbw[4], pnbb[4], pbias[4];
        float w0[4], w1[4], w2[4];
        const float heR = 0.03f * 0.04419417382415922f;
        #pragma unroll
        for (int fn = 0; fn < 4; ++fn) {
            int n = n0 + (wn << 6) + (fn << 4) + l15;
            nIdx[fn] = n;
            pdg[fn] = dgb[n]; pnsw[fn] = nsw[n]; pnsb[fn] = nsb[n];
            pnbw[fn] = nbw[n]; pnbb[fn] = nbb[n]; pbias[fn] = biasv[n];
            w0[fn] = rgbwv[n] * heR;
            w1[fn] = rgbwv[CC + n] * heR;
            w2[fn] = rgbwv[2*CC + n] * heR;
        }
        #pragma unroll
        for (int fm = 0; fm < 8; ++fm) {
            const int mbase = m0 + (wm << 7) + (fm << 4) + ((lane >> 4) << 2);
            const f32x4 nsv = *(const f32x4*)(noise + mbase);
            f32x4 pc0 = {0.f,0.f,0.f,0.f}, pc1 = {0.f,0.f,0.f,0.f}, pc2 = {0.f,0.f,0.f,0.f};
            #pragma unroll
            for (int fn = 0; fn < 4; ++fn) {
                f32x4 vv;
                #pragma unroll
                for (int r = 0; r < 4; ++r) {
                    float ns = nsv[r];
                    float v = acc[fm][fn][r] * pdg[fn];
                    v = v * (ns*pnsw[fn] + pnsb[fn]) + (ns*pnbw[fn] + pnbb[fn]) + pbias[fn];
                    vv[r] = fmaxf(v, 0.2f*v);
                }
                pc0 += vv * w0[fn]; pc1 += vv * w1[fn]; pc2 += vv * w2[fn];
                *(f32x4*)(outf + ((size_t)(b*CC + nIdx[fn]) << 12) + (mbase & 4095)) = vv;
            }
            // rgb partial: reduce over the 16 l15 lanes (they hold this wave's 64 ch)
            #pragma unroll
            for (int r = 0; r < 4; ++r) {
                float a0 = pc0[r], a1 = pc1[r], a2 = pc2[r];
                #pragma unroll
                for (int mk = 1; mk < 16; mk <<= 1) {
                    a0 += __shfl_xor(a0, mk);
                    a1 += __shfl_xor(a1, mk);
                    a2 += __shfl_xor(a2, mk);
                }
                if (l15 == 0) {
                    int px = (mbase + r) & 4095;
                    atomicAdd(outrgb + (b*3 + 0)*4096 + px, a0);
                    atomicAdd(outrgb + (b*3 + 1)*4096 + px, a1);
                    atomicAdd(outrgb + (b*3 + 2)*4096 + px, a2);
                }
            }
        }
    }
}

extern "C" void kernel_launch(void* const* d_in, const int* in_sizes, int n_in,
                              void* d_out, int out_size, void* d_ws, size_t ws_size,
                              hipStream_t stream) {
    const float* x      = (const float*)d_in[0];
    const float* w      = (const float*)d_in[1];
    const float* noise1 = (const float*)d_in[2];
    const float* noise2 = (const float*)d_in[3];
    const float* conv1w = (const float*)d_in[4];
    const float* bias1  = (const float*)d_in[5];
    const float* conv2w = (const float*)d_in[6];
    const float* bias2  = (const float*)d_in[7];
    const float* A1w = (const float*)d_in[8];
    const float* A1b = (const float*)d_in[9];
    const float* A2w = (const float*)d_in[10];
    const float* A2b = (const float*)d_in[11];
    const float* B1sw = (const float*)d_in[12];
    const float* B1sb = (const float*)d_in[13];
    const float* B1bw = (const float*)d_in[14];
    const float* B1bb = (const float*)d_in[15];
    const float* B2sw = (const float*)d_in[16];
    const float* B2sb = (const float*)d_in[17];
    const float* B2bw = (const float*)d_in[18];
    const float* B2bb = (const float*)d_in[19];
    const float* rgbw = (const float*)d_in[20];
    const float* rgbb = (const float*)d_in[21];

    char* ws = (char*)d_ws;
    size_t off = 0;
    auto alloc = [&](size_t bytes) { char* p = ws + off; off += (bytes + 255) & ~(size_t)255; return p; };
    const size_t xsBytes = (size_t)BB*HP*HP*CC*2;
    bf16* xs1 = (bf16*)alloc(xsBytes);
    bf16* xs2 = (bf16*)alloc(xsBytes);
    bf16* kT1 = (bf16*)alloc((size_t)9*CC*CC*2);
    bf16* kT2 = (bf16*)alloc((size_t)9*CC*CC*2);
    float* S21 = (float*)alloc((size_t)CC*CC*4);
    float* S22 = (float*)alloc((size_t)CC*CC*4);
    float* s1  = (float*)alloc(BB*CC*4);
    float* s2  = (float*)alloc(BB*CC*4);
    float* dg1 = (float*)alloc(BB*CC*4);
    float* dg2 = (float*)alloc(BB*CC*4);

    float* outx   = (float*)d_out;
    float* outrgb = outx + (size_t)BB*CC*HO*HO;

    const float gain = 1.41421356237309515f;
    const float he = gain / sqrtf(512.f * 9.f);
    halo_zero<<<4160, 64, 0, stream>>>(xs1, xs2);
    rgb_init<<<96, 256, 0, stream>>>(rgbb, outrgb);
    prep_weights<<<CC*CC/256, 256, 0, stream>>>(conv1w, S21, kT1, he);
    prep_weights<<<CC*CC/256, 256, 0, stream>>>(conv2w, S22, kT2, he);
    style_kernel<<<2*BB*CC/4, 256, 0, stream>>>(w, A1w, A1b, A2w, A2b, s1, s2);
    demod_kernel<<<2*BB*CC/4, 256, 0, stream>>>(s1, S21, s2, S22, dg1, dg2, gain);
    upsample_mod<<<BB*HO*16, CC, 0, stream>>>(x, s1, xs1);
    conv_gemm<1><<<(NPIX/256)*(CC/256), 512, 0, stream>>>(
        xs1, kT1, dg1, noise1, B1sw, B1sb, B1bw, B1bb, bias1, s2, xs2, nullptr,
        nullptr, nullptr);
    conv_gemm<2><<<(NPIX/256)*(CC/256), 512, 0, stream>>>(
        xs2, kT2, dg2, noise2, B2sw, B2sb, B2bw, B2bb, bias2, nullptr, nullptr, outx,
        rgbw, outrgb);
}

// Round 9
// 355.668 us; speedup vs baseline: 1.0101x; 1.0101x over previous
//
#include <hip/hip_runtime.h>
#include <hip/hip_bf16.h>

#define BB 8
#define CC 512
#define HO 64
#define HP 66
#define NPIX (BB*HO*HO)   // 32768

typedef float f32x4 __attribute__((ext_vector_type(4)));
typedef __bf16 bf16x8 __attribute__((ext_vector_type(8)));
using bf16 = __hip_bfloat16;

__device__ __forceinline__ void gload16(const void* g, void* l) {
    __builtin_amdgcn_global_load_lds((const __attribute__((address_space(1))) void*)g,
                                     (__attribute__((address_space(3))) void*)l, 16, 0, 0);
}

__device__ __forceinline__ float waveRedSum(float v) {
    #pragma unroll
    for (int off = 32; off; off >>= 1) v += __shfl_down(v, off);
    return v;
}

// thread t -> (i = t&511, o = t>>9). Reads W[i][o][0..8] (contiguous 36B),
// writes S2ho[o][i] = he^2 * sum W^2, and keffT[tap][o][i] = he*W[i][o][8-tap].
__global__ void prep_weights(const float* __restrict__ Wsrc, float* __restrict__ S2ho,
                             bf16* __restrict__ keffT, float he) {
    int t = blockIdx.x * blockDim.x + threadIdx.x;
    int i = t & (CC-1), o = t >> 9;
    const float* wp = Wsrc + (i*CC + o)*9;
    float v[9]; float s2 = 0.f;
    #pragma unroll
    for (int k = 0; k < 9; ++k) { v[k] = wp[k] * he; s2 += v[k]*v[k]; }
    S2ho[o*CC + i] = s2;
    #pragma unroll
    for (int tp = 0; tp < 9; ++tp) keffT[(tp*CC + o)*CC + i] = (bf16)v[8 - tp];
}

// one wave per (set, b, i): style[b,i] = sum_d w[b,d]*A[i,d]/sqrt(512) + Ab[i]
__global__ void style_kernel(const float* __restrict__ w,
                             const float* __restrict__ A1, const float* __restrict__ A1b,
                             const float* __restrict__ A2, const float* __restrict__ A2b,
                             float* __restrict__ s1, float* __restrict__ s2) {
    int wid = (blockIdx.x * blockDim.x + threadIdx.x) >> 6;
    int lane = threadIdx.x & 63;
    int set = wid >= BB*CC; int rem = set ? wid - BB*CC : wid;
    int b = rem >> 9, i = rem & (CC-1);
    const float* A = set ? A2 : A1;
    const float* wb = w + b*CC;
    float sum = 0.f;
    for (int d = lane; d < CC; d += 64) sum += wb[d] * A[i*CC + d];
    sum = waveRedSum(sum);
    if (lane == 0) {
        float r = sum * 0.04419417382415922f + (set ? A2b : A1b)[i];
        (set ? s2 : s1)[b*CC + i] = r;
    }
}

// one wave per (set, b, o): dg = gain * rsqrt(sum_i style^2 * S2ho[o][i] + eps)
__global__ void demod_kernel(const float* __restrict__ s1, const float* __restrict__ S21,
                             const float* __restrict__ s2, const float* __restrict__ S22,
                             float* __restrict__ dg1, float* __restrict__ dg2, float gain) {
    int wid = (blockIdx.x * blockDim.x + threadIdx.x) >> 6;
    int lane = threadIdx.x & 63;
    int set = wid >= BB*CC; int rem = set ? wid - BB*CC : wid;
    int b = rem >> 9, o = rem & (CC-1);
    const float* st = (set ? s2 : s1) + b*CC;
    const float* S2 = (set ? S22 : S21) + o*CC;
    float sum = 0.f;
    for (int i = lane; i < CC; i += 64) { float sv = st[i]; sum += sv*sv*S2[i]; }
    sum = waveRedSum(sum);
    if (lane == 0) (set ? dg2 : dg1)[b*CC + o] = gain * rsqrtf(sum + 1e-8f);
}

// block = (b, p, q-group of 4), 512 threads = channels.
__global__ void upsample_mod(const float* __restrict__ x, const float* __restrict__ s1,
                             bf16* __restrict__ xs1) {
    __shared__ float usl[16][CC];
    int blk = blockIdx.x;
    int i = threadIdx.x;
    int b = blk >> 10, rem = blk & 1023, p = rem >> 4, q0 = (rem & 15) << 2;
    const float scale = 31.0f / 63.0f;
    float chf = p * scale; int h0 = (int)chf; float fh = chf - h0; int h1 = min(h0 + 1, 31);
    int wa = min(((int)(q0 * scale)) & ~3, 24);    // 4-aligned, wa+7 <= 31
    const float* xb = x + ((size_t)(b*CC + i) << 10);
    f32x4 r00 = *(const f32x4*)(xb + (h0 << 5) + wa);
    f32x4 r01 = *(const f32x4*)(xb + (h0 << 5) + wa + 4);
    f32x4 r10 = *(const f32x4*)(xb + (h1 << 5) + wa);
    f32x4 r11 = *(const f32x4*)(xb + (h1 << 5) + wa + 4);
    #pragma unroll
    for (int k = 0; k < 4; ++k) {
        usl[k][i] = r00[k]; usl[4 + k][i] = r01[k];
        usl[8 + k][i] = r10[k]; usl[12 + k][i] = r11[k];
    }
    float sv = s1[b*CC + i];
    #pragma unroll
    for (int dq = 0; dq < 4; ++dq) {
        int q = q0 + dq;
        float cwf = q * scale; int w0 = (int)cwf; float fw = cwf - w0;
        int i0 = w0 - wa, i1 = min(w0 + 1, 31) - wa;
        float v00 = usl[i0][i], v01 = usl[i1][i];
        float v10 = usl[8 + i0][i], v11 = usl[8 + i1][i];
        float va = v00*(1.f-fh) + v10*fh;
        float vb = v01*(1.f-fh) + v11*fh;
        float v  = (va*(1.f-fw) + vb*fw) * sv;
        xs1[(((b*HP) + p + 1)*HP + (q + 1))*CC + i] = (bf16)v;
    }
}

// zero only the 1-pixel halo ring of xs1/xs2 (replaces 2x 35.7MB memset).
__global__ void halo_zero(bf16* __restrict__ xs1, bf16* __restrict__ xs2) {
    int blk = blockIdx.x;
    bf16* dst = (blk & 1) ? xs2 : xs1;
    int idx = blk >> 1;                 // 0..2079
    int b = idx / 260, rm = idx - b*260;
    int p, q;
    if (rm < 66)       { p = 0;        q = rm; }
    else if (rm < 132) { p = 65;       q = rm - 66; }
    else if (rm < 196) { p = rm - 131; q = 0; }
    else               { p = rm - 195; q = 65; }
    f32x4* d4 = (f32x4*)(dst + ((size_t)((b*HP + p)*HP + q)) * CC);
    d4[threadIdx.x] = f32x4{0.f, 0.f, 0.f, 0.f};
}

// init outrgb planes with rgbb[c] (fused rgb accumulates on top via atomics).
// outrgb layout: [(b*3+c)*4096 + px]; 24 planes of 4096 f32.
__global__ void rgb_init(const float* __restrict__ rgbb, float* __restrict__ outrgb) {
    int t = blockIdx.x * blockDim.x + threadIdx.x;   // 24*1024 threads, f32x4 each
    int plane = t >> 10, c = plane - (plane/3)*3;
    float v = rgbb[c];
    *(f32x4*)(outrgb + (plane << 12) + ((t & 1023) << 2)) = f32x4{v, v, v, v};
}

// ---------------------------------------------------------------------------
// Implicit-GEMM 3x3 conv, m201-faithful 8-phase schedule (T2+T3+T4+T5).
// BM=BN=256, BK=64, 512 thr = 8 waves (2Mx4N), per-wave 128x64.
// K-loop + PHASE1 epilogue verbatim from r7 (conv1 best: 156 us, MfmaUtil 42%,
// WRITE 67MB). [r8's swapped-operand uint2 epilogue REGRESSED: WRITE 81.6MB,
// +4.5us — scattered 8B stores across 16 pixel-lines merge worse than r7's
// channel-contiguous 2B run. Reverted.]
// PHASE2 keeps r8's FUSED rgb (net −8.5us vs separate rgb_kernel): pc[c] +=
// v*rgbw[c,n]*he, shfl_xor reduce over 16 l15 lanes, atomicAdd into outrgb
// (pre-initialized with rgbb by rgb_init).
// ---------------------------------------------------------------------------
#define SB  __builtin_amdgcn_sched_barrier(0)
#define BAR __builtin_amdgcn_s_barrier()
#define VMC(n)  asm volatile("s_waitcnt vmcnt(" #n ")" ::: "memory")
#define LGKM(n) asm volatile("s_waitcnt lgkmcnt(" #n ")" ::: "memory")

#define STAGE_A(d, h, U) do { \
    gload16((U) + aThr + (h)*(HP*1024),                 ldsA + (d)*32768 + (h)*16384); \
    gload16((U) + aThr + (h)*(HP*1024) + 2*(HP*1024),   ldsA + (d)*32768 + (h)*16384 + 8192); \
} while (0)

#define STAGE_B(d, h, U) do { \
    gload16((U) + bThr + (h)*32768,                     ldsB + (d)*32768 + (h)*16384); \
    gload16((U) + bThr + (h)*32768 + 131072,            ldsB + (d)*32768 + (h)*16384 + 8192); \
} while (0)

#define LOAD_A(d, fh) do { \
    _Pragma("unroll") \
    for (int fmq = 0; fmq < 4; ++fmq) { \
        afr[fmq][0] = *(const bf16x8*)(aRd + (d)*32768 + (fh)*16384 + fmq*2048 + swz0); \
        afr[fmq][1] = *(const bf16x8*)(aRd + (d)*32768 + (fh)*16384 + fmq*2048 + swz1); \
    } } while (0)

#define LOAD_B(d, nh) do { \
    _Pragma("unroll") \
    for (int fnq = 0; fnq < 2; ++fnq) { \
        bfr[nh][fnq][0] = *(const bf16x8*)(bRd + (d)*32768 + (nh)*16384 + fnq*2048 + swz0); \
        bfr[nh][fnq][1] = *(const bf16x8*)(bRd + (d)*32768 + (nh)*16384 + fnq*2048 + swz1); \
    } } while (0)

#define QUAD(fh, nh) do { \
    __builtin_amdgcn_s_setprio(1); \
    _Pragma("unroll") \
    for (int kc = 0; kc < 2; ++kc) \
    { _Pragma("unroll") \
      for (int fmq = 0; fmq < 4; ++fmq) \
      { _Pragma("unroll") \
        for (int fnq = 0; fnq < 2; ++fnq) \
            acc[(fh)*4+fmq][(nh)*2+fnq] = __builtin_amdgcn_mfma_f32_16x16x32_bf16( \
                afr[fmq][kc], bfr[nh][fnq][kc], acc[(fh)*4+fmq][(nh)*2+fnq], 0, 0, 0); } } \
    __builtin_amdgcn_s_setprio(0); } while (0)

// one K-step = 4 phases. cur/nxt are dbuf indices (compile-time).
#define PHSTEP(cur, nxt, aN1, bN1, aN2, g1, g3) do { \
    /* phase 0: Q(0,0) */ \
    LOAD_A(cur, 0); \
    LOAD_B(cur, 0); \
    if (g1) STAGE_B(nxt, 0, bN1); \
    LGKM(8); SB; BAR; LGKM(0); SB; \
    QUAD(0, 0); \
    VMC(4); SB; BAR; SB; \
    /* phase 1: Q(0,1) */ \
    LOAD_B(cur, 1); \
    if (g1) STAGE_B(nxt, 1, bN1); \
    SB; BAR; LGKM(0); SB; \
    QUAD(0, 1); \
    SB; BAR; SB; \
    /* phase 2: Q(1,1) */ \
    LOAD_A(cur, 1); \
    if (g1) STAGE_A(nxt, 1, aN1); \
    SB; BAR; LGKM(0); SB; \
    QUAD(1, 1); \
    SB; BAR; SB; \
    /* phase 3: Q(1,0) */ \
    if (g3) STAGE_A(cur, 0, aN2); \
    SB; BAR; SB; \
    QUAD(1, 0); \
    if (g3) { VMC(6); } else { VMC(0); } \
    SB; BAR; SB; \
} while (0)

template<int PHASE>
__global__ __launch_bounds__(512, 2) void conv_gemm(
    const bf16* __restrict__ xs, const bf16* __restrict__ keffT,
    const float* __restrict__ dg, const float* __restrict__ noise,
    const float* __restrict__ nsw, const float* __restrict__ nsb,
    const float* __restrict__ nbw, const float* __restrict__ nbb,
    const float* __restrict__ biasv, const float* __restrict__ stnext,
    bf16* __restrict__ outb, float* __restrict__ outf,
    const float* __restrict__ rgbwv, float* __restrict__ outrgb) {
    __shared__ __attribute__((aligned(16))) bf16 As[32768];   // 64 KB: 2 dbuf x 256x64
    __shared__ __attribute__((aligned(16))) bf16 Bs[32768];   // 64 KB
    const int tid = threadIdx.x;
    const int wave = tid >> 6, lane = tid & 63;
    // XCD swizzle: 256 wgs, %8==0 -> bijective.
    const int tileId = ((blockIdx.x & 7) << 5) + (blockIdx.x >> 3);
    const int mtile = tileId >> 1, ntile = tileId & 1;
    const int m0 = mtile << 8, n0 = ntile << 8;
    const int b  = m0 >> 12;
    const int p0 = (m0 & 4095) >> 6;
    const int wm = wave >> 2, wn = wave & 3;
    const int l15 = lane & 15;

    // staging thread constants (source pre-XOR-swizzled, dest linear)
    const int srcSwz = (((tid & 7) ^ ((tid >> 3) & 7)) << 4);
    const int aThr = ((tid >> 3) << 10) + srcSwz;
    const int bThr = (((tid >> 8) & 1) << 16) + (((tid >> 3) & 31) << 10) + srcSwz;
    char* const ldsA = (char*)As + tid*16;
    char* const ldsB = (char*)Bs + tid*16;

    // fragment read bases (row*128 + (slot ^ row&7)*16)
    const char* const aRd = (const char*)As + (((wm << 6) + l15) << 7);
    const char* const bRd = (const char*)Bs + (((wn << 5) + l15) << 7);
    const int swz0 = (((lane >> 4)    ) ^ (lane & 7)) << 4;
    const int swz1 = (((lane >> 4) | 4) ^ (lane & 7)) << 4;

    f32x4 acc[8][4];
    #pragma unroll
    for (int i_ = 0; i_ < 8; ++i_)
        #pragma unroll
        for (int j_ = 0; j_ < 4; ++j_) acc[i_][j_] = f32x4{0.f, 0.f, 0.f, 0.f};
    bf16x8 afr[4][2], bfr[2][2][2];

    // uniform staging bases per K-step st (0..71): tap t=st>>3, k0=(st&7)*64
    auto abase = [&](int st) -> const char* {
        int t = st >> 3; int dh = (t*11) >> 5; int dw = t - dh*3;
        return (const char*)xs + ((size_t)((b*HP + p0 + dh)*HP + dw) << 10) + ((st & 7) << 7);
    };
    auto bbase = [&](int st) -> const char* {
        int t = st >> 3;
        return (const char*)keffT + ((size_t)(t*CC + n0) << 10) + ((st & 7) << 7);
    };

    // prologue: stage units 0..4 in read order, leave units 2..4 in flight
    {
        const char* a0 = abase(0); const char* b0 = bbase(0); const char* a1 = abase(1);
        STAGE_A(0, 0, a0);
        STAGE_B(0, 0, b0);
        STAGE_B(0, 1, b0);
        STAGE_A(0, 1, a0);
        STAGE_A(1, 0, a1);
        VMC(6); SB; BAR; SB;
    }

    #pragma unroll 1
    for (int it = 0; it < 36; ++it) {
        const bool more = (it < 35);
        const char* aE = abase(2*it + 1); const char* bE = bbase(2*it + 1);
        const char* aO = abase(2*it + 2); const char* bO = bbase(2*it + 2);
        const char* aO2 = abase(2*it + 3);
        PHSTEP(0, 1, aE, bE, aO,  true, more);   // compute K-step 2it   (dbuf0)
        PHSTEP(1, 0, aO, bO, aO2, more, more);   // compute K-step 2it+1 (dbuf1)
    }

    // epilogue: v*dg -> noise modulation -> +bias -> lrelu -> route
    // layout: px = m0+wm*128+fm*16+(lane>>4)*4+r; ch = n0+wn*64+fn*16+l15
    const float* dgb = dg + b*CC;
    int nIdx[4]; float pdg[4], pnsw[4], pnsb[4], pnbw[4], pnbb[4], pbias[4];
    float pst[4], w0[4], w1[4], w2[4];
    const float heR = 0.03f * 0.04419417382415922f;
    #pragma unroll
    for (int fn = 0; fn < 4; ++fn) {
        int n = n0 + (wn << 6) + (fn << 4) + l15;
        nIdx[fn] = n;
        pdg[fn] = dgb[n]; pnsw[fn] = nsw[n]; pnsb[fn] = nsb[n];
        pnbw[fn] = nbw[n]; pnbb[fn] = nbb[n]; pbias[fn] = biasv[n];
        if constexpr (PHASE == 1) {
            pst[fn] = stnext[b*CC + n];
        } else {
            pst[fn] = 0.f;
            w0[fn] = rgbwv[n] * heR;
            w1[fn] = rgbwv[CC + n] * heR;
            w2[fn] = rgbwv[2*CC + n] * heR;
        }
    }
    #pragma unroll
    for (int fm = 0; fm < 8; ++fm) {
        const int mbase = m0 + (wm << 7) + (fm << 4) + ((lane >> 4) << 2);
        const f32x4 nsv = *(const f32x4*)(noise + mbase);   // 4 consecutive pixels
        if constexpr (PHASE == 2) {
            f32x4 pc0 = {0.f,0.f,0.f,0.f}, pc1 = {0.f,0.f,0.f,0.f}, pc2 = {0.f,0.f,0.f,0.f};
            #pragma unroll
            for (int fn = 0; fn < 4; ++fn) {
                f32x4 vv;
                #pragma unroll
                for (int r = 0; r < 4; ++r) {
                    float ns = nsv[r];
                    float v = acc[fm][fn][r] * pdg[fn];
                    v = v * (ns*pnsw[fn] + pnsb[fn]) + (ns*pnbw[fn] + pnbb[fn]) + pbias[fn];
                    vv[r] = fmaxf(v, 0.2f*v);
                }
                pc0 += vv * w0[fn]; pc1 += vv * w1[fn]; pc2 += vv * w2[fn];
                *(f32x4*)(outf + ((size_t)(b*CC + nIdx[fn]) << 12) + (mbase & 4095)) = vv;
            }
            // rgb partial: reduce over the 16 l15 lanes (they hold this wave's 64 ch)
            #pragma unroll
            for (int r = 0; r < 4; ++r) {
                float a0 = pc0[r], a1 = pc1[r], a2 = pc2[r];
                #pragma unroll
                for (int mk = 1; mk < 16; mk <<= 1) {
                    a0 += __shfl_xor(a0, mk);
                    a1 += __shfl_xor(a1, mk);
                    a2 += __shfl_xor(a2, mk);
                }
                if (l15 == 0) {
                    int px = (mbase + r) & 4095;
                    atomicAdd(outrgb + (b*3 + 0)*4096 + px, a0);
                    atomicAdd(outrgb + (b*3 + 1)*4096 + px, a1);
                    atomicAdd(outrgb + (b*3 + 2)*4096 + px, a2);
                }
            }
        } else {
            #pragma unroll
            for (int r = 0; r < 4; ++r) {
                int mloc = mbase + r;
                float ns = nsv[r];
                int prow = (mloc & 4095) >> 6, qcol = mloc & 63;
                #pragma unroll
                for (int fn = 0; fn < 4; ++fn) {
                    float v = acc[fm][fn][r] * pdg[fn];
                    v = v * (ns*pnsw[fn] + pnsb[fn]) + (ns*pnbw[fn] + pnbb[fn]) + pbias[fn];
                    v = fmaxf(v, 0.2f*v);   // leaky relu 0.2
                    outb[(((b*HP) + prow + 1)*HP + (qcol + 1))*CC + nIdx[fn]] =
                        (bf16)(v * pst[fn]);
                }
            }
        }
    }
}

extern "C" void kernel_launch(void* const* d_in, const int* in_sizes, int n_in,
                              void* d_out, int out_size, void* d_ws, size_t ws_size,
                              hipStream_t stream) {
    const float* x      = (const float*)d_in[0];
    const float* w      = (const float*)d_in[1];
    const float* noise1 = (const float*)d_in[2];
    const float* noise2 = (const float*)d_in[3];
    const float* conv1w = (const float*)d_in[4];
    const float* bias1  = (const float*)d_in[5];
    const float* conv2w = (const float*)d_in[6];
    const float* bias2  = (const float*)d_in[7];
    const float* A1w = (const float*)d_in[8];
    const float* A1b = (const float*)d_in[9];
    const float* A2w = (const float*)d_in[10];
    const float* A2b = (const float*)d_in[11];
    const float* B1sw = (const float*)d_in[12];
    const float* B1sb = (const float*)d_in[13];
    const float* B1bw = (const float*)d_in[14];
    const float* B1bb = (const float*)d_in[15];
    const float* B2sw = (const float*)d_in[16];
    const float* B2sb = (const float*)d_in[17];
    const float* B2bw = (const float*)d_in[18];
    const float* B2bb = (const float*)d_in[19];
    const float* rgbw = (const float*)d_in[20];
    const float* rgbb = (const float*)d_in[21];

    char* ws = (char*)d_ws;
    size_t off = 0;
    auto alloc = [&](size_t bytes) { char* p = ws + off; off += (bytes + 255) & ~(size_t)255; return p; };
    const size_t xsBytes = (size_t)BB*HP*HP*CC*2;
    bf16* xs1 = (bf16*)alloc(xsBytes);
    bf16* xs2 = (bf16*)alloc(xsBytes);
    bf16* kT1 = (bf16*)alloc((size_t)9*CC*CC*2);
    bf16* kT2 = (bf16*)alloc((size_t)9*CC*CC*2);
    float* S21 = (float*)alloc((size_t)CC*CC*4);
    float* S22 = (float*)alloc((size_t)CC*CC*4);
    float* s1  = (float*)alloc(BB*CC*4);
    float* s2  = (float*)alloc(BB*CC*4);
    float* dg1 = (float*)alloc(BB*CC*4);
    float* dg2 = (float*)alloc(BB*CC*4);

    float* outx   = (float*)d_out;
    float* outrgb = outx + (size_t)BB*CC*HO*HO;

    const float gain = 1.41421356237309515f;
    const float he = gain / sqrtf(512.f * 9.f);
    halo_zero<<<4160, 64, 0, stream>>>(xs1, xs2);
    rgb_init<<<96, 256, 0, stream>>>(rgbb, outrgb);
    prep_weights<<<CC*CC/256, 256, 0, stream>>>(conv1w, S21, kT1, he);
    prep_weights<<<CC*CC/256, 256, 0, stream>>>(conv2w, S22, kT2, he);
    style_kernel<<<2*BB*CC/4, 256, 0, stream>>>(w, A1w, A1b, A2w, A2b, s1, s2);
    demod_kernel<<<2*BB*CC/4, 256, 0, stream>>>(s1, S21, s2, S22, dg1, dg2, gain);
    upsample_mod<<<BB*HO*16, CC, 0, stream>>>(x, s1, xs1);
    conv_gemm<1><<<(NPIX/256)*(CC/256), 512, 0, stream>>>(
        xs1, kT1, dg1, noise1, B1sw, B1sb, B1bw, B1bb, bias1, s2, xs2, nullptr,
        nullptr, nullptr);
    conv_gemm<2><<<(NPIX/256)*(CC/256), 512, 0, stream>>>(
        xs2, kT2, dg2, noise2, B2sw, B2sb, B2bw, B2bb, bias2, nullptr, nullptr, outx,
        rgbw, outrgb);
}

// Round 10
// 351.924 us; speedup vs baseline: 1.0208x; 1.0106x over previous
//
#include <hip/hip_runtime.h>
#include <hip/hip_bf16.h>

#define BB 8
#define CC 512
#define HO 64
#define HP 66
#define NPIX (BB*HO*HO)   // 32768

typedef float f32x4 __attribute__((ext_vector_type(4)));
typedef __bf16 bf16x8 __attribute__((ext_vector_type(8)));
using bf16 = __hip_bfloat16;

__device__ __forceinline__ void gload16(const void* g, void* l) {
    __builtin_amdgcn_global_load_lds((const __attribute__((address_space(1))) void*)g,
                                     (__attribute__((address_space(3))) void*)l, 16, 0, 0);
}

__device__ __forceinline__ float waveRedSum(float v) {
    #pragma unroll
    for (int off = 32; off; off >>= 1) v += __shfl_down(v, off);
    return v;
}

// thread t -> (i = t&511, o = t>>9). Reads W[i][o][0..8] (contiguous 36B),
// writes S2ho[o][i] = he^2 * sum W^2, and keffT[tap][o][i] = he*W[i][o][8-tap].
__global__ void prep_weights(const float* __restrict__ Wsrc, float* __restrict__ S2ho,
                             bf16* __restrict__ keffT, float he) {
    int t = blockIdx.x * blockDim.x + threadIdx.x;
    int i = t & (CC-1), o = t >> 9;
    const float* wp = Wsrc + (i*CC + o)*9;
    float v[9]; float s2 = 0.f;
    #pragma unroll
    for (int k = 0; k < 9; ++k) { v[k] = wp[k] * he; s2 += v[k]*v[k]; }
    S2ho[o*CC + i] = s2;
    #pragma unroll
    for (int tp = 0; tp < 9; ++tp) keffT[(tp*CC + o)*CC + i] = (bf16)v[8 - tp];
}

// one wave per (set, b, i): style[b,i] = sum_d w[b,d]*A[i,d]/sqrt(512) + Ab[i]
__global__ void style_kernel(const float* __restrict__ w,
                             const float* __restrict__ A1, const float* __restrict__ A1b,
                             const float* __restrict__ A2, const float* __restrict__ A2b,
                             float* __restrict__ s1, float* __restrict__ s2) {
    int wid = (blockIdx.x * blockDim.x + threadIdx.x) >> 6;
    int lane = threadIdx.x & 63;
    int set = wid >= BB*CC; int rem = set ? wid - BB*CC : wid;
    int b = rem >> 9, i = rem & (CC-1);
    const float* A = set ? A2 : A1;
    const float* wb = w + b*CC;
    float sum = 0.f;
    for (int d = lane; d < CC; d += 64) sum += wb[d] * A[i*CC + d];
    sum = waveRedSum(sum);
    if (lane == 0) {
        float r = sum * 0.04419417382415922f + (set ? A2b : A1b)[i];
        (set ? s2 : s1)[b*CC + i] = r;
    }
}

// one wave per (set, b, o): dg = gain * rsqrt(sum_i style^2 * S2ho[o][i] + eps)
__global__ void demod_kernel(const float* __restrict__ s1, const float* __restrict__ S21,
                             const float* __restrict__ s2, const float* __restrict__ S22,
                             float* __restrict__ dg1, float* __restrict__ dg2, float gain) {
    int wid = (blockIdx.x * blockDim.x + threadIdx.x) >> 6;
    int lane = threadIdx.x & 63;
    int set = wid >= BB*CC; int rem = set ? wid - BB*CC : wid;
    int b = rem >> 9, o = rem & (CC-1);
    const float* st = (set ? s2 : s1) + b*CC;
    const float* S2 = (set ? S22 : S21) + o*CC;
    float sum = 0.f;
    for (int i = lane; i < CC; i += 64) { float sv = st[i]; sum += sv*sv*S2[i]; }
    sum = waveRedSum(sum);
    if (lane == 0) (set ? dg2 : dg1)[b*CC + o] = gain * rsqrtf(sum + 1e-8f);
}

// block = (b, p, q-group of 4), 512 threads = channels.
__global__ void upsample_mod(const float* __restrict__ x, const float* __restrict__ s1,
                             bf16* __restrict__ xs1) {
    __shared__ float usl[16][CC];
    int blk = blockIdx.x;
    int i = threadIdx.x;
    int b = blk >> 10, rem = blk & 1023, p = rem >> 4, q0 = (rem & 15) << 2;
    const float scale = 31.0f / 63.0f;
    float chf = p * scale; int h0 = (int)chf; float fh = chf - h0; int h1 = min(h0 + 1, 31);
    int wa = min(((int)(q0 * scale)) & ~3, 24);    // 4-aligned, wa+7 <= 31
    const float* xb = x + ((size_t)(b*CC + i) << 10);
    f32x4 r00 = *(const f32x4*)(xb + (h0 << 5) + wa);
    f32x4 r01 = *(const f32x4*)(xb + (h0 << 5) + wa + 4);
    f32x4 r10 = *(const f32x4*)(xb + (h1 << 5) + wa);
    f32x4 r11 = *(const f32x4*)(xb + (h1 << 5) + wa + 4);
    #pragma unroll
    for (int k = 0; k < 4; ++k) {
        usl[k][i] = r00[k]; usl[4 + k][i] = r01[k];
        usl[8 + k][i] = r10[k]; usl[12 + k][i] = r11[k];
    }
    float sv = s1[b*CC + i];
    #pragma unroll
    for (int dq = 0; dq < 4; ++dq) {
        int q = q0 + dq;
        float cwf = q * scale; int w0 = (int)cwf; float fw = cwf - w0;
        int i0 = w0 - wa, i1 = min(w0 + 1, 31) - wa;
        float v00 = usl[i0][i], v01 = usl[i1][i];
        float v10 = usl[8 + i0][i], v11 = usl[8 + i1][i];
        float va = v00*(1.f-fh) + v10*fh;
        float vb = v01*(1.f-fh) + v11*fh;
        float v  = (va*(1.f-fw) + vb*fw) * sv;
        xs1[(((b*HP) + p + 1)*HP + (q + 1))*CC + i] = (bf16)v;
    }
}

// blocks 0..4159: zero the 1-pixel halo ring of xs1/xs2 (replaces 2x 35.7MB
// memset). blocks 4160..4543: init outrgb planes with rgbb[c] (fused rgb
// accumulates on top via atomics). 64 threads, 16B each.
__global__ void halo_rgb_init(bf16* __restrict__ xs1, bf16* __restrict__ xs2,
                              const float* __restrict__ rgbb, float* __restrict__ outrgb) {
    int blk = blockIdx.x;
    if (blk >= 4160) {
        int t = blk - 4160;                       // 0..383, 16 blocks per plane
        int plane = t >> 4;                       // 0..23
        int c = plane - (plane/3)*3;
        float v = rgbb[c];
        *(f32x4*)(outrgb + (plane << 12) + ((t & 15) << 8) + (threadIdx.x << 2)) =
            f32x4{v, v, v, v};
        return;
    }
    bf16* dst = (blk & 1) ? xs2 : xs1;
    int idx = blk >> 1;                 // 0..2079
    int b = idx / 260, rm = idx - b*260;
    int p, q;
    if (rm < 66)       { p = 0;        q = rm; }
    else if (rm < 132) { p = 65;       q = rm - 66; }
    else if (rm < 196) { p = rm - 131; q = 0; }
    else               { p = rm - 195; q = 65; }
    f32x4* d4 = (f32x4*)(dst + ((size_t)((b*HP + p)*HP + q)) * CC);
    d4[threadIdx.x] = f32x4{0.f, 0.f, 0.f, 0.f};
}

// ---------------------------------------------------------------------------
// Implicit-GEMM 3x3 conv, m201-faithful 8-phase schedule (T2+T3+T4+T5).
// BM=BN=256, BK=64, 512 thr = 8 waves (2Mx4N), per-wave 128x64.
// K-loop verbatim from r3/r7 (best measured: 156 us, MfmaUtil ~41%, 0 confl).
// Split into TWO standalone kernels (not a shared template): co-compiled
// template instantiations share regalloc context (guide rule #19) — conv2's
// rgb-fusion epilogue must not perturb conv1's K-loop codegen.
// ---------------------------------------------------------------------------
#define SB  __builtin_amdgcn_sched_barrier(0)
#define BAR __builtin_amdgcn_s_barrier()
#define VMC(n)  asm volatile("s_waitcnt vmcnt(" #n ")" ::: "memory")
#define LGKM(n) asm volatile("s_waitcnt lgkmcnt(" #n ")" ::: "memory")

#define STAGE_A(d, h, U) do { \
    gload16((U) + aThr + (h)*(HP*1024),                 ldsA + (d)*32768 + (h)*16384); \
    gload16((U) + aThr + (h)*(HP*1024) + 2*(HP*1024),   ldsA + (d)*32768 + (h)*16384 + 8192); \
} while (0)

#define STAGE_B(d, h, U) do { \
    gload16((U) + bThr + (h)*32768,                     ldsB + (d)*32768 + (h)*16384); \
    gload16((U) + bThr + (h)*32768 + 131072,            ldsB + (d)*32768 + (h)*16384 + 8192); \
} while (0)

#define LOAD_A(d, fh) do { \
    _Pragma("unroll") \
    for (int fmq = 0; fmq < 4; ++fmq) { \
        afr[fmq][0] = *(const bf16x8*)(aRd + (d)*32768 + (fh)*16384 + fmq*2048 + swz0); \
        afr[fmq][1] = *(const bf16x8*)(aRd + (d)*32768 + (fh)*16384 + fmq*2048 + swz1); \
    } } while (0)

#define LOAD_B(d, nh) do { \
    _Pragma("unroll") \
    for (int fnq = 0; fnq < 2; ++fnq) { \
        bfr[nh][fnq][0] = *(const bf16x8*)(bRd + (d)*32768 + (nh)*16384 + fnq*2048 + swz0); \
        bfr[nh][fnq][1] = *(const bf16x8*)(bRd + (d)*32768 + (nh)*16384 + fnq*2048 + swz1); \
    } } while (0)

#define QUAD(fh, nh) do { \
    __builtin_amdgcn_s_setprio(1); \
    _Pragma("unroll") \
    for (int kc = 0; kc < 2; ++kc) \
    { _Pragma("unroll") \
      for (int fmq = 0; fmq < 4; ++fmq) \
      { _Pragma("unroll") \
        for (int fnq = 0; fnq < 2; ++fnq) \
            acc[(fh)*4+fmq][(nh)*2+fnq] = __builtin_amdgcn_mfma_f32_16x16x32_bf16( \
                afr[fmq][kc], bfr[nh][fnq][kc], acc[(fh)*4+fmq][(nh)*2+fnq], 0, 0, 0); } } \
    __builtin_amdgcn_s_setprio(0); } while (0)

// one K-step = 4 phases. cur/nxt are dbuf indices (compile-time).
#define PHSTEP(cur, nxt, aN1, bN1, aN2, g1, g3) do { \
    /* phase 0: Q(0,0) */ \
    LOAD_A(cur, 0); \
    LOAD_B(cur, 0); \
    if (g1) STAGE_B(nxt, 0, bN1); \
    LGKM(8); SB; BAR; LGKM(0); SB; \
    QUAD(0, 0); \
    VMC(4); SB; BAR; SB; \
    /* phase 1: Q(0,1) */ \
    LOAD_B(cur, 1); \
    if (g1) STAGE_B(nxt, 1, bN1); \
    SB; BAR; LGKM(0); SB; \
    QUAD(0, 1); \
    SB; BAR; SB; \
    /* phase 2: Q(1,1) */ \
    LOAD_A(cur, 1); \
    if (g1) STAGE_A(nxt, 1, aN1); \
    SB; BAR; LGKM(0); SB; \
    QUAD(1, 1); \
    SB; BAR; SB; \
    /* phase 3: Q(1,0) */ \
    if (g3) STAGE_A(cur, 0, aN2); \
    SB; BAR; SB; \
    QUAD(1, 0); \
    if (g3) { VMC(6); } else { VMC(0); } \
    SB; BAR; SB; \
} while (0)

// shared preamble + K-loop (expands inside each kernel body)
#define CONV_COMMON \
    __shared__ __attribute__((aligned(16))) bf16 As[32768]; \
    __shared__ __attribute__((aligned(16))) bf16 Bs[32768]; \
    const int tid = threadIdx.x; \
    const int wave = tid >> 6, lane = tid & 63; \
    const int tileId = ((blockIdx.x & 7) << 5) + (blockIdx.x >> 3); \
    const int mtile = tileId >> 1, ntile = tileId & 1; \
    const int m0 = mtile << 8, n0 = ntile << 8; \
    const int b  = m0 >> 12; \
    const int p0 = (m0 & 4095) >> 6; \
    const int wm = wave >> 2, wn = wave & 3; \
    const int l15 = lane & 15; \
    const int srcSwz = (((tid & 7) ^ ((tid >> 3) & 7)) << 4); \
    const int aThr = ((tid >> 3) << 10) + srcSwz; \
    const int bThr = (((tid >> 8) & 1) << 16) + (((tid >> 3) & 31) << 10) + srcSwz; \
    char* const ldsA = (char*)As + tid*16; \
    char* const ldsB = (char*)Bs + tid*16; \
    const char* const aRd = (const char*)As + (((wm << 6) + l15) << 7); \
    const char* const bRd = (const char*)Bs + (((wn << 5) + l15) << 7); \
    const int swz0 = (((lane >> 4)    ) ^ (lane & 7)) << 4; \
    const int swz1 = (((lane >> 4) | 4) ^ (lane & 7)) << 4; \
    f32x4 acc[8][4]; \
    _Pragma("unroll") \
    for (int i_ = 0; i_ < 8; ++i_) \
        _Pragma("unroll") \
        for (int j_ = 0; j_ < 4; ++j_) acc[i_][j_] = f32x4{0.f, 0.f, 0.f, 0.f}; \
    bf16x8 afr[4][2], bfr[2][2][2]; \
    auto abase = [&](int st) -> const char* { \
        int t = st >> 3; int dh = (t*11) >> 5; int dw = t - dh*3; \
        return (const char*)xs + ((size_t)((b*HP + p0 + dh)*HP + dw) << 10) + ((st & 7) << 7); \
    }; \
    auto bbase = [&](int st) -> const char* { \
        int t = st >> 3; \
        return (const char*)keffT + ((size_t)(t*CC + n0) << 10) + ((st & 7) << 7); \
    }; \
    { \
        const char* a0 = abase(0); const char* b0 = bbase(0); const char* a1 = abase(1); \
        STAGE_A(0, 0, a0); \
        STAGE_B(0, 0, b0); \
        STAGE_B(0, 1, b0); \
        STAGE_A(0, 1, a0); \
        STAGE_A(1, 0, a1); \
        VMC(6); SB; BAR; SB; \
    } \
    _Pragma("unroll 1") \
    for (int it = 0; it < 36; ++it) { \
        const bool more = (it < 35); \
        const char* aE = abase(2*it + 1); const char* bE = bbase(2*it + 1); \
        const char* aO = abase(2*it + 2); const char* bO = bbase(2*it + 2); \
        const char* aO2 = abase(2*it + 3); \
        PHSTEP(0, 1, aE, bE, aO,  true, more); \
        PHSTEP(1, 0, aO, bO, aO2, more, more); \
    }

// conv1: writes bf16 padded-NHWC xs2 (pre-multiplied by next style).
__global__ __launch_bounds__(512, 2) void conv_gemm1(
    const bf16* __restrict__ xs, const bf16* __restrict__ keffT,
    const float* __restrict__ dg, const float* __restrict__ noise,
    const float* __restrict__ nsw, const float* __restrict__ nsb,
    const float* __restrict__ nbw, const float* __restrict__ nbb,
    const float* __restrict__ biasv, const float* __restrict__ stnext,
    bf16* __restrict__ outb) {
    CONV_COMMON
    // epilogue: px = m0+wm*128+fm*16+(lane>>4)*4+r; ch = n0+wn*64+fn*16+l15
    const float* dgb = dg + b*CC;
    int nIdx[4]; float pdg[4], pnsw[4], pnsb[4], pnbw[4], pnbb[4], pbias[4], pst[4];
    #pragma unroll
    for (int fn = 0; fn < 4; ++fn) {
        int n = n0 + (wn << 6) + (fn << 4) + l15;
        nIdx[fn] = n;
        pdg[fn] = dgb[n]; pnsw[fn] = nsw[n]; pnsb[fn] = nsb[n];
        pnbw[fn] = nbw[n]; pnbb[fn] = nbb[n]; pbias[fn] = biasv[n];
        pst[fn] = stnext[b*CC + n];
    }
    #pragma unroll
    for (int fm = 0; fm < 8; ++fm) {
        const int mbase = m0 + (wm << 7) + (fm << 4) + ((lane >> 4) << 2);
        const f32x4 nsv = *(const f32x4*)(noise + mbase);
        #pragma unroll
        for (int r = 0; r < 4; ++r) {
            int mloc = mbase + r;
            float ns = nsv[r];
            int prow = (mloc & 4095) >> 6, qcol = mloc & 63;
            #pragma unroll
            for (int fn = 0; fn < 4; ++fn) {
                float v = acc[fm][fn][r] * pdg[fn];
                v = v * (ns*pnsw[fn] + pnsb[fn]) + (ns*pnbw[fn] + pnbb[fn]) + pbias[fn];
                v = fmaxf(v, 0.2f*v);   // leaky relu 0.2
                outb[(((b*HP) + prow + 1)*HP + (qcol + 1))*CC + nIdx[fn]] =
                    (bf16)(v * pst[fn]);
            }
        }
    }
}

// conv2: writes f32 NCHW outx + fused rgb (atomics spread over lanes 0..2).
__global__ __launch_bounds__(512, 2) void conv_gemm2(
    const bf16* __restrict__ xs, const bf16* __restrict__ keffT,
    const float* __restrict__ dg, const float* __restrict__ noise,
    const float* __restrict__ nsw, const float* __restrict__ nsb,
    const float* __restrict__ nbw, const float* __restrict__ nbb,
    const float* __restrict__ biasv, float* __restrict__ outf,
    const float* __restrict__ rgbwv, float* __restrict__ outrgb) {
    CONV_COMMON
    const float* dgb = dg + b*CC;
    int nIdx[4]; float pdg[4], pnsw[4], pnsb[4], pnbw[4], pnbb[4], pbias[4];
    float w0[4], w1[4], w2[4];
    const float heR = 0.03f * 0.04419417382415922f;
    #pragma unroll
    for (int fn = 0; fn < 4; ++fn) {
        int n = n0 + (wn << 6) + (fn << 4) + l15;
        nIdx[fn] = n;
        pdg[fn] = dgb[n]; pnsw[fn] = nsw[n]; pnsb[fn] = nsb[n];
        pnbw[fn] = nbw[n]; pnbb[fn] = nbb[n]; pbias[fn] = biasv[n];
        w0[fn] = rgbwv[n] * heR;
        w1[fn] = rgbwv[CC + n] * heR;
        w2[fn] = rgbwv[2*CC + n] * heR;
    }
    #pragma unroll
    for (int fm = 0; fm < 8; ++fm) {
        const int mbase = m0 + (wm << 7) + (fm << 4) + ((lane >> 4) << 2);
        const f32x4 nsv = *(const f32x4*)(noise + mbase);
        f32x4 pc0 = {0.f,0.f,0.f,0.f}, pc1 = {0.f,0.f,0.f,0.f}, pc2 = {0.f,0.f,0.f,0.f};
        #pragma unroll
        for (int fn = 0; fn < 4; ++fn) {
            f32x4 vv;
            #pragma unroll
            for (int r = 0; r < 4; ++r) {
                float ns = nsv[r];
                float v = acc[fm][fn][r] * pdg[fn];
                v = v * (ns*pnsw[fn] + pnsb[fn]) + (ns*pnbw[fn] + pnbb[fn]) + pbias[fn];
                vv[r] = fmaxf(v, 0.2f*v);
            }
            pc0 += vv * w0[fn]; pc1 += vv * w1[fn]; pc2 += vv * w2[fn];
            *(f32x4*)(outf + ((size_t)(b*CC + nIdx[fn]) << 12) + (mbase & 4095)) = vv;
        }
        // rgb partial: butterfly over the 16 l15 lanes -> all lanes hold sums;
        // lanes 0..2 each issue one atomic (3x less per-lane serialization).
        #pragma unroll
        for (int r = 0; r < 4; ++r) {
            float a0 = pc0[r], a1 = pc1[r], a2 = pc2[r];
            #pragma unroll
            for (int mk = 1; mk < 16; mk <<= 1) {
                a0 += __shfl_xor(a0, mk);
                a1 += __shfl_xor(a1, mk);
                a2 += __shfl_xor(a2, mk);
            }
            if (l15 < 3) {
                float av = (l15 == 0) ? a0 : (l15 == 1) ? a1 : a2;
                int px = (mbase + r) & 4095;
                atomicAdd(outrgb + (b*3 + l15)*4096 + px, av);
            }
        }
    }
}

extern "C" void kernel_launch(void* const* d_in, const int* in_sizes, int n_in,
                              void* d_out, int out_size, void* d_ws, size_t ws_size,
                              hipStream_t stream) {
    const float* x      = (const float*)d_in[0];
    const float* w      = (const float*)d_in[1];
    const float* noise1 = (const float*)d_in[2];
    const float* noise2 = (const float*)d_in[3];
    const float* conv1w = (const float*)d_in[4];
    const float* bias1  = (const float*)d_in[5];
    const float* conv2w = (const float*)d_in[6];
    const float* bias2  = (const float*)d_in[7];
    const float* A1w = (const float*)d_in[8];
    const float* A1b = (const float*)d_in[9];
    const float* A2w = (const float*)d_in[10];
    const float* A2b = (const float*)d_in[11];
    const float* B1sw = (const float*)d_in[12];
    const float* B1sb = (const float*)d_in[13];
    const float* B1bw = (const float*)d_in[14];
    const float* B1bb = (const float*)d_in[15];
    const float* B2sw = (const float*)d_in[16];
    const float* B2sb = (const float*)d_in[17];
    const float* B2bw = (const float*)d_in[18];
    const float* B2bb = (const float*)d_in[19];
    const float* rgbw = (const float*)d_in[20];
    const float* rgbb = (const float*)d_in[21];

    char* ws = (char*)d_ws;
    size_t off = 0;
    auto alloc = [&](size_t bytes) { char* p = ws + off; off += (bytes + 255) & ~(size_t)255; return p; };
    const size_t xsBytes = (size_t)BB*HP*HP*CC*2;
    bf16* xs1 = (bf16*)alloc(xsBytes);
    bf16* xs2 = (bf16*)alloc(xsBytes);
    bf16* kT1 = (bf16*)alloc((size_t)9*CC*CC*2);
    bf16* kT2 = (bf16*)alloc((size_t)9*CC*CC*2);
    float* S21 = (float*)alloc((size_t)CC*CC*4);
    float* S22 = (float*)alloc((size_t)CC*CC*4);
    float* s1  = (float*)alloc(BB*CC*4);
    float* s2  = (float*)alloc(BB*CC*4);
    float* dg1 = (float*)alloc(BB*CC*4);
    float* dg2 = (float*)alloc(BB*CC*4);

    float* outx   = (float*)d_out;
    float* outrgb = outx + (size_t)BB*CC*HO*HO;

    const float gain = 1.41421356237309515f;
    const float he = gain / sqrtf(512.f * 9.f);
    halo_rgb_init<<<4544, 64, 0, stream>>>(xs1, xs2, rgbb, outrgb);
    prep_weights<<<CC*CC/256, 256, 0, stream>>>(conv1w, S21, kT1, he);
    prep_weights<<<CC*CC/256, 256, 0, stream>>>(conv2w, S22, kT2, he);
    style_kernel<<<2*BB*CC/4, 256, 0, stream>>>(w, A1w, A1b, A2w, A2b, s1, s2);
    demod_kernel<<<2*BB*CC/4, 256, 0, stream>>>(s1, S21, s2, S22, dg1, dg2, gain);
    upsample_mod<<<BB*HO*16, CC, 0, stream>>>(x, s1, xs1);
    conv_gemm1<<<(NPIX/256)*(CC/256), 512, 0, stream>>>(
        xs1, kT1, dg1, noise1, B1sw, B1sb, B1bw, B1bb, bias1, s2, xs2);
    conv_gemm2<<<(NPIX/256)*(CC/256), 512, 0, stream>>>(
        xs2, kT2, dg2, noise2, B2sw, B2sb, B2bw, B2bb, bias2, outx, rgbw, outrgb);
}

// Round 11
// 323.716 us; speedup vs baseline: 1.1098x; 1.0871x over previous
//
#include <hip/hip_runtime.h>
#include <hip/hip_bf16.h>

#define BB 8
#define CC 512
#define HO 64
#define HP 66
#define NPIX (BB*HO*HO)   // 32768

typedef float f32x4 __attribute__((ext_vector_type(4)));
typedef __bf16 bf16x8 __attribute__((ext_vector_type(8)));
using bf16 = __hip_bfloat16;

__device__ __forceinline__ void gload16(const void* g, void* l) {
    __builtin_amdgcn_global_load_lds((const __attribute__((address_space(1))) void*)g,
                                     (__attribute__((address_space(3))) void*)l, 16, 0, 0);
}

__device__ __forceinline__ float waveRedSum(float v) {
    #pragma unroll
    for (int off = 32; off; off >>= 1) v += __shfl_down(v, off);
    return v;
}

// ---------------------------------------------------------------------------
// init_all: one launch, 256 threads, three independent jobs branch on blockIdx:
//  [0,2048)     prep_weights for conv1 (first 1024) / conv2 (next 1024):
//               thread t -> (i=t&511, o=t>>9); reads W[i][o][0..8] (36B),
//               writes S2ho[o][i] = he^2*sum W^2, keffT[tap][o][i]=he*W[8-tap].
//  [2048,3088)  halo zero of xs1/xs2 (4 halo pixels per block; replaces the
//               former 2x 35.7MB memset).
//  [3088,3184)  outrgb init with rgbb[c] (fused rgb atomics accumulate on top).
// ---------------------------------------------------------------------------
__global__ void init_all(const float* __restrict__ W1, const float* __restrict__ W2,
                         float* __restrict__ S21, float* __restrict__ S22,
                         bf16* __restrict__ kT1, bf16* __restrict__ kT2, float he,
                         bf16* __restrict__ xs1, bf16* __restrict__ xs2,
                         const float* __restrict__ rgbb, float* __restrict__ outrgb) {
    int blk = blockIdx.x, tid = threadIdx.x;
    if (blk < 2048) {
        int which = blk >> 10;
        const float* Wsrc = which ? W2 : W1;
        float* S2ho = which ? S22 : S21;
        bf16* keffT = which ? kT2 : kT1;
        int t = ((blk & 1023) << 8) + tid;
        int i = t & (CC-1), o = t >> 9;
        const float* wp = Wsrc + (i*CC + o)*9;
        float v[9]; float s2 = 0.f;
        #pragma unroll
        for (int k = 0; k < 9; ++k) { v[k] = wp[k] * he; s2 += v[k]*v[k]; }
        S2ho[o*CC + i] = s2;
        #pragma unroll
        for (int tp = 0; tp < 9; ++tp) keffT[(tp*CC + o)*CC + i] = (bf16)v[8 - tp];
    } else if (blk < 3088) {
        int sub = ((blk - 2048) << 2) + (tid >> 6);   // 0..4159
        int ln = tid & 63;
        bf16* dst = (sub & 1) ? xs2 : xs1;
        int idx = sub >> 1;                 // 0..2079
        int b = idx / 260, rm = idx - b*260;
        int p, q;
        if (rm < 66)       { p = 0;        q = rm; }
        else if (rm < 132) { p = 65;       q = rm - 66; }
        else if (rm < 196) { p = rm - 131; q = 0; }
        else               { p = rm - 195; q = 65; }
        f32x4* d4 = (f32x4*)(dst + ((size_t)((b*HP + p)*HP + q)) * CC);
        d4[ln] = f32x4{0.f, 0.f, 0.f, 0.f};
    } else {
        int t2 = ((blk - 3088) << 2) + (tid >> 6);    // 0..383
        int plane = t2 >> 4;                          // 0..23
        int c = plane - (plane/3)*3;
        float v = rgbb[c];
        *(f32x4*)(outrgb + (plane << 12) + ((t2 & 15) << 8) + ((tid & 63) << 2)) =
            f32x4{v, v, v, v};
    }
}

// one wave per (set, b, i): style[b,i] = sum_d w[b,d]*A[i,d]/sqrt(512) + Ab[i]
__global__ void style_kernel(const float* __restrict__ w,
                             const float* __restrict__ A1, const float* __restrict__ A1b,
                             const float* __restrict__ A2, const float* __restrict__ A2b,
                             float* __restrict__ s1, float* __restrict__ s2) {
    int wid = (blockIdx.x * blockDim.x + threadIdx.x) >> 6;
    int lane = threadIdx.x & 63;
    int set = wid >= BB*CC; int rem = set ? wid - BB*CC : wid;
    int b = rem >> 9, i = rem & (CC-1);
    const float* A = set ? A2 : A1;
    const float* wb = w + b*CC;
    float sum = 0.f;
    for (int d = lane; d < CC; d += 64) sum += wb[d] * A[i*CC + d];
    sum = waveRedSum(sum);
    if (lane == 0) {
        float r = sum * 0.04419417382415922f + (set ? A2b : A1b)[i];
        (set ? s2 : s1)[b*CC + i] = r;
    }
}

// one wave per (set, b, o): dg = gain * rsqrt(sum_i style^2 * S2ho[o][i] + eps)
__global__ void demod_kernel(const float* __restrict__ s1, const float* __restrict__ S21,
                             const float* __restrict__ s2, const float* __restrict__ S22,
                             float* __restrict__ dg1, float* __restrict__ dg2, float gain) {
    int wid = (blockIdx.x * blockDim.x + threadIdx.x) >> 6;
    int lane = threadIdx.x & 63;
    int set = wid >= BB*CC; int rem = set ? wid - BB*CC : wid;
    int b = rem >> 9, o = rem & (CC-1);
    const float* st = (set ? s2 : s1) + b*CC;
    const float* S2 = (set ? S22 : S21) + o*CC;
    float sum = 0.f;
    for (int i = lane; i < CC; i += 64) { float sv = st[i]; sum += sv*sv*S2[i]; }
    sum = waveRedSum(sum);
    if (lane == 0) (set ? dg2 : dg1)[b*CC + o] = gain * rsqrtf(sum + 1e-8f);
}

// block = (b, p): one full output row, 512 threads = channels.
// H-lerp hoisted: m[w] = x[h0][w]*(1-fh) + x[h1][w]*fh computed once per
// thread into usl[32][CC] (64KB; bank = ch%32, 2-way = free; no barrier --
// each thread reads only its own column). q-loop fully unrolled -> w0/w1/fw
// compile-time -> static-offset ds_read_b32 + 3 VALU per output.
// 4x less global traffic than the 4-pixel-group version (64MB vs 268MB).
__global__ void upsample_mod(const float* __restrict__ x, const float* __restrict__ s1,
                             bf16* __restrict__ xs1) {
    __shared__ float usl[32][CC];
    int blk = blockIdx.x;                  // b*64 + p
    int i = threadIdx.x;
    int b = blk >> 6, p = blk & 63;
    const float scale = 31.0f / 63.0f;
    float chf = p * scale; int h0 = (int)chf; float fh = chf - h0; int h1 = min(h0 + 1, 31);
    const float* xb = x + ((size_t)(b*CC + i) << 10);
    #pragma unroll
    for (int k = 0; k < 8; ++k) {
        f32x4 r0 = *(const f32x4*)(xb + (h0 << 5) + (k << 2));
        f32x4 r1 = *(const f32x4*)(xb + (h1 << 5) + (k << 2));
        #pragma unroll
        for (int e = 0; e < 4; ++e)
            usl[(k << 2) + e][i] = r0[e]*(1.f - fh) + r1[e]*fh;
    }
    float sv = s1[b*CC + i];
    bf16* op = xs1 + ((size_t)((b*HP + p + 1)*HP + 1))*CC + i;
    #pragma unroll
    for (int q = 0; q < 64; ++q) {
        float cwf = q * scale; int w0 = (int)cwf; float fw = cwf - w0;
        int w1 = min(w0 + 1, 31);
        float v = (usl[w0][i]*(1.f - fw) + usl[w1][i]*fw) * sv;
        op[q*CC] = (bf16)v;
    }
}

// ---------------------------------------------------------------------------
// Implicit-GEMM 3x3 conv, m201-faithful 8-phase schedule (T2+T3+T4+T5).
// BM=BN=256, BK=64, 512 thr = 8 waves (2Mx4N), per-wave 128x64.
// K-loop + epilogues verbatim from r10 (best measured: conv1 ~156.5us,
// conv2 ~158.5us, MfmaUtil ~41.5%, 0 bank conflicts). Two standalone
// kernels (rule #19: no shared-template regalloc coupling).
// ---------------------------------------------------------------------------
#define SB  __builtin_amdgcn_sched_barrier(0)
#define BAR __builtin_amdgcn_s_barrier()
#define VMC(n)  asm volatile("s_waitcnt vmcnt(" #n ")" ::: "memory")
#define LGKM(n) asm volatile("s_waitcnt lgkmcnt(" #n ")" ::: "memory")

#define STAGE_A(d, h, U) do { \
    gload16((U) + aThr + (h)*(HP*1024),                 ldsA + (d)*32768 + (h)*16384); \
    gload16((U) + aThr + (h)*(HP*1024) + 2*(HP*1024),   ldsA + (d)*32768 + (h)*16384 + 8192); \
} while (0)

#define STAGE_B(d, h, U) do { \
    gload16((U) + bThr + (h)*32768,                     ldsB + (d)*32768 + (h)*16384); \
    gload16((U) + bThr + (h)*32768 + 131072,            ldsB + (d)*32768 + (h)*16384 + 8192); \
} while (0)

#define LOAD_A(d, fh) do { \
    _Pragma("unroll") \
    for (int fmq = 0; fmq < 4; ++fmq) { \
        afr[fmq][0] = *(const bf16x8*)(aRd + (d)*32768 + (fh)*16384 + fmq*2048 + swz0); \
        afr[fmq][1] = *(const bf16x8*)(aRd + (d)*32768 + (fh)*16384 + fmq*2048 + swz1); \
    } } while (0)

#define LOAD_B(d, nh) do { \
    _Pragma("unroll") \
    for (int fnq = 0; fnq < 2; ++fnq) { \
        bfr[nh][fnq][0] = *(const bf16x8*)(bRd + (d)*32768 + (nh)*16384 + fnq*2048 + swz0); \
        bfr[nh][fnq][1] = *(const bf16x8*)(bRd + (d)*32768 + (nh)*16384 + fnq*2048 + swz1); \
    } } while (0)

#define QUAD(fh, nh) do { \
    __builtin_amdgcn_s_setprio(1); \
    _Pragma("unroll") \
    for (int kc = 0; kc < 2; ++kc) \
    { _Pragma("unroll") \
      for (int fmq = 0; fmq < 4; ++fmq) \
      { _Pragma("unroll") \
        for (int fnq = 0; fnq < 2; ++fnq) \
            acc[(fh)*4+fmq][(nh)*2+fnq] = __builtin_amdgcn_mfma_f32_16x16x32_bf16( \
                afr[fmq][kc], bfr[nh][fnq][kc], acc[(fh)*4+fmq][(nh)*2+fnq], 0, 0, 0); } } \
    __builtin_amdgcn_s_setprio(0); } while (0)

// one K-step = 4 phases. cur/nxt are dbuf indices (compile-time).
#define PHSTEP(cur, nxt, aN1, bN1, aN2, g1, g3) do { \
    /* phase 0: Q(0,0) */ \
    LOAD_A(cur, 0); \
    LOAD_B(cur, 0); \
    if (g1) STAGE_B(nxt, 0, bN1); \
    LGKM(8); SB; BAR; LGKM(0); SB; \
    QUAD(0, 0); \
    VMC(4); SB; BAR; SB; \
    /* phase 1: Q(0,1) */ \
    LOAD_B(cur, 1); \
    if (g1) STAGE_B(nxt, 1, bN1); \
    SB; BAR; LGKM(0); SB; \
    QUAD(0, 1); \
    SB; BAR; SB; \
    /* phase 2: Q(1,1) */ \
    LOAD_A(cur, 1); \
    if (g1) STAGE_A(nxt, 1, aN1); \
    SB; BAR; LGKM(0); SB; \
    QUAD(1, 1); \
    SB; BAR; SB; \
    /* phase 3: Q(1,0) */ \
    if (g3) STAGE_A(cur, 0, aN2); \
    SB; BAR; SB; \
    QUAD(1, 0); \
    if (g3) { VMC(6); } else { VMC(0); } \
    SB; BAR; SB; \
} while (0)

// shared preamble + K-loop (expands inside each kernel body)
#define CONV_COMMON \
    __shared__ __attribute__((aligned(16))) bf16 As[32768]; \
    __shared__ __attribute__((aligned(16))) bf16 Bs[32768]; \
    const int tid = threadIdx.x; \
    const int wave = tid >> 6, lane = tid & 63; \
    const int tileId = ((blockIdx.x & 7) << 5) + (blockIdx.x >> 3); \
    const int mtile = tileId >> 1, ntile = tileId & 1; \
    const int m0 = mtile << 8, n0 = ntile << 8; \
    const int b  = m0 >> 12; \
    const int p0 = (m0 & 4095) >> 6; \
    const int wm = wave >> 2, wn = wave & 3; \
    const int l15 = lane & 15; \
    const int srcSwz = (((tid & 7) ^ ((tid >> 3) & 7)) << 4); \
    const int aThr = ((tid >> 3) << 10) + srcSwz; \
    const int bThr = (((tid >> 8) & 1) << 16) + (((tid >> 3) & 31) << 10) + srcSwz; \
    char* const ldsA = (char*)As + tid*16; \
    char* const ldsB = (char*)Bs + tid*16; \
    const char* const aRd = (const char*)As + (((wm << 6) + l15) << 7); \
    const char* const bRd = (const char*)Bs + (((wn << 5) + l15) << 7); \
    const int swz0 = (((lane >> 4)    ) ^ (lane & 7)) << 4; \
    const int swz1 = (((lane >> 4) | 4) ^ (lane & 7)) << 4; \
    f32x4 acc[8][4]; \
    _Pragma("unroll") \
    for (int i_ = 0; i_ < 8; ++i_) \
        _Pragma("unroll") \
        for (int j_ = 0; j_ < 4; ++j_) acc[i_][j_] = f32x4{0.f, 0.f, 0.f, 0.f}; \
    bf16x8 afr[4][2], bfr[2][2][2]; \
    auto abase = [&](int st) -> const char* { \
        int t = st >> 3; int dh = (t*11) >> 5; int dw = t - dh*3; \
        return (const char*)xs + ((size_t)((b*HP + p0 + dh)*HP + dw) << 10) + ((st & 7) << 7); \
    }; \
    auto bbase = [&](int st) -> const char* { \
        int t = st >> 3; \
        return (const char*)keffT + ((size_t)(t*CC + n0) << 10) + ((st & 7) << 7); \
    }; \
    { \
        const char* a0 = abase(0); const char* b0 = bbase(0); const char* a1 = abase(1); \
        STAGE_A(0, 0, a0); \
        STAGE_B(0, 0, b0); \
        STAGE_B(0, 1, b0); \
        STAGE_A(0, 1, a0); \
        STAGE_A(1, 0, a1); \
        VMC(6); SB; BAR; SB; \
    } \
    _Pragma("unroll 1") \
    for (int it = 0; it < 36; ++it) { \
        const bool more = (it < 35); \
        const char* aE = abase(2*it + 1); const char* bE = bbase(2*it + 1); \
        const char* aO = abase(2*it + 2); const char* bO = bbase(2*it + 2); \
        const char* aO2 = abase(2*it + 3); \
        PHSTEP(0, 1, aE, bE, aO,  true, more); \
        PHSTEP(1, 0, aO, bO, aO2, more, more); \
    }

// conv1: writes bf16 padded-NHWC xs2 (pre-multiplied by next style).
__global__ __launch_bounds__(512, 2) void conv_gemm1(
    const bf16* __restrict__ xs, const bf16* __restrict__ keffT,
    const float* __restrict__ dg, const float* __restrict__ noise,
    const float* __restrict__ nsw, const float* __restrict__ nsb,
    const float* __restrict__ nbw, const float* __restrict__ nbb,
    const float* __restrict__ biasv, const float* __restrict__ stnext,
    bf16* __restrict__ outb) {
    CONV_COMMON
    // epilogue: px = m0+wm*128+fm*16+(lane>>4)*4+r; ch = n0+wn*64+fn*16+l15
    const float* dgb = dg + b*CC;
    int nIdx[4]; float pdg[4], pnsw[4], pnsb[4], pnbw[4], pnbb[4], pbias[4], pst[4];
    #pragma unroll
    for (int fn = 0; fn < 4; ++fn) {
        int n = n0 + (wn << 6) + (fn << 4) + l15;
        nIdx[fn] = n;
        pdg[fn] = dgb[n]; pnsw[fn] = nsw[n]; pnsb[fn] = nsb[n];
        pnbw[fn] = nbw[n]; pnbb[fn] = nbb[n]; pbias[fn] = biasv[n];
        pst[fn] = stnext[b*CC + n];
    }
    #pragma unroll
    for (int fm = 0; fm < 8; ++fm) {
        const int mbase = m0 + (wm << 7) + (fm << 4) + ((lane >> 4) << 2);
        const f32x4 nsv = *(const f32x4*)(noise + mbase);
        #pragma unroll
        for (int r = 0; r < 4; ++r) {
            int mloc = mbase + r;
            float ns = nsv[r];
            int prow = (mloc & 4095) >> 6, qcol = mloc & 63;
            #pragma unroll
            for (int fn = 0; fn < 4; ++fn) {
                float v = acc[fm][fn][r] * pdg[fn];
                v = v * (ns*pnsw[fn] + pnsb[fn]) + (ns*pnbw[fn] + pnbb[fn]) + pbias[fn];
                v = fmaxf(v, 0.2f*v);   // leaky relu 0.2
                outb[(((b*HP) + prow + 1)*HP + (qcol + 1))*CC + nIdx[fn]] =
                    (bf16)(v * pst[fn]);
            }
        }
    }
}

// conv2: writes f32 NCHW outx + fused rgb (atomics spread over lanes 0..2).
__global__ __launch_bounds__(512, 2) void conv_gemm2(
    const bf16* __restrict__ xs, const bf16* __restrict__ keffT,
    const float* __restrict__ dg, const float* __restrict__ noise,
    const float* __restrict__ nsw, const float* __restrict__ nsb,
    const float* __restrict__ nbw, const float* __restrict__ nbb,
    const float* __restrict__ biasv, float* __restrict__ outf,
    const float* __restrict__ rgbwv, float* __restrict__ outrgb) {
    CONV_COMMON
    const float* dgb = dg + b*CC;
    int nIdx[4]; float pdg[4], pnsw[4], pnsb[4], pnbw[4], pnbb[4], pbias[4];
    float w0[4], w1[4], w2[4];
    const float heR = 0.03f * 0.04419417382415922f;
    #pragma unroll
    for (int fn = 0; fn < 4; ++fn) {
        int n = n0 + (wn << 6) + (fn << 4) + l15;
        nIdx[fn] = n;
        pdg[fn] = dgb[n]; pnsw[fn] = nsw[n]; pnsb[fn] = nsb[n];
        pnbw[fn] = nbw[n]; pnbb[fn] = nbb[n]; pbias[fn] = biasv[n];
        w0[fn] = rgbwv[n] * heR;
        w1[fn] = rgbwv[CC + n] * heR;
        w2[fn] = rgbwv[2*CC + n] * heR;
    }
    #pragma unroll
    for (int fm = 0; fm < 8; ++fm) {
        const int mbase = m0 + (wm << 7) + (fm << 4) + ((lane >> 4) << 2);
        const f32x4 nsv = *(const f32x4*)(noise + mbase);
        f32x4 pc0 = {0.f,0.f,0.f,0.f}, pc1 = {0.f,0.f,0.f,0.f}, pc2 = {0.f,0.f,0.f,0.f};
        #pragma unroll
        for (int fn = 0; fn < 4; ++fn) {
            f32x4 vv;
            #pragma unroll
            for (int r = 0; r < 4; ++r) {
                float ns = nsv[r];
                float v = acc[fm][fn][r] * pdg[fn];
                v = v * (ns*pnsw[fn] + pnsb[fn]) + (ns*pnbw[fn] + pnbb[fn]) + pbias[fn];
                vv[r] = fmaxf(v, 0.2f*v);
            }
            pc0 += vv * w0[fn]; pc1 += vv * w1[fn]; pc2 += vv * w2[fn];
            *(f32x4*)(outf + ((size_t)(b*CC + nIdx[fn]) << 12) + (mbase & 4095)) = vv;
        }
        // rgb partial: butterfly over the 16 l15 lanes -> all lanes hold sums;
        // lanes 0..2 each issue one atomic (3x less per-lane serialization).
        #pragma unroll
        for (int r = 0; r < 4; ++r) {
            float a0 = pc0[r], a1 = pc1[r], a2 = pc2[r];
            #pragma unroll
            for (int mk = 1; mk < 16; mk <<= 1) {
                a0 += __shfl_xor(a0, mk);
                a1 += __shfl_xor(a1, mk);
                a2 += __shfl_xor(a2, mk);
            }
            if (l15 < 3) {
                float av = (l15 == 0) ? a0 : (l15 == 1) ? a1 : a2;
                int px = (mbase + r) & 4095;
                atomicAdd(outrgb + (b*3 + l15)*4096 + px, av);
            }
        }
    }
}

extern "C" void kernel_launch(void* const* d_in, const int* in_sizes, int n_in,
                              void* d_out, int out_size, void* d_ws, size_t ws_size,
                              hipStream_t stream) {
    const float* x      = (const float*)d_in[0];
    const float* w      = (const float*)d_in[1];
    const float* noise1 = (const float*)d_in[2];
    const float* noise2 = (const float*)d_in[3];
    const float* conv1w = (const float*)d_in[4];
    const float* bias1  = (const float*)d_in[5];
    const float* conv2w = (const float*)d_in[6];
    const float* bias2  = (const float*)d_in[7];
    const float* A1w = (const float*)d_in[8];
    const float* A1b = (const float*)d_in[9];
    const float* A2w = (const float*)d_in[10];
    const float* A2b = (const float*)d_in[11];
    const float* B1sw = (const float*)d_in[12];
    const float* B1sb = (const float*)d_in[13];
    const float* B1bw = (const float*)d_in[14];
    const float* B1bb = (const float*)d_in[15];
    const float* B2sw = (const float*)d_in[16];
    const float* B2sb = (const float*)d_in[17];
    const float* B2bw = (const float*)d_in[18];
    const float* B2bb = (const float*)d_in[19];
    const float* rgbw = (const float*)d_in[20];
    const float* rgbb = (const float*)d_in[21];

    char* ws = (char*)d_ws;
    size_t off = 0;
    auto alloc = [&](size_t bytes) { char* p = ws + off; off += (bytes + 255) & ~(size_t)255; return p; };
    const size_t xsBytes = (size_t)BB*HP*HP*CC*2;
    bf16* xs1 = (bf16*)alloc(xsBytes);
    bf16* xs2 = (bf16*)alloc(xsBytes);
    bf16* kT1 = (bf16*)alloc((size_t)9*CC*CC*2);
    bf16* kT2 = (bf16*)alloc((size_t)9*CC*CC*2);
    float* S21 = (float*)alloc((size_t)CC*CC*4);
    float* S22 = (float*)alloc((size_t)CC*CC*4);
    float* s1  = (float*)alloc(BB*CC*4);
    float* s2  = (float*)alloc(BB*CC*4);
    float* dg1 = (float*)alloc(BB*CC*4);
    float* dg2 = (float*)alloc(BB*CC*4);

    float* outx   = (float*)d_out;
    float* outrgb = outx + (size_t)BB*CC*HO*HO;

    const float gain = 1.41421356237309515f;
    const float he = gain / sqrtf(512.f * 9.f);
    init_all<<<3184, 256, 0, stream>>>(conv1w, conv2w, S21, S22, kT1, kT2, he,
                                       xs1, xs2, rgbb, outrgb);
    style_kernel<<<2*BB*CC/4, 256, 0, stream>>>(w, A1w, A1b, A2w, A2b, s1, s2);
    demod_kernel<<<2*BB*CC/4, 256, 0, stream>>>(s1, S21, s2, S22, dg1, dg2, gain);
    upsample_mod<<<BB*HO, CC, 0, stream>>>(x, s1, xs1);
    conv_gemm1<<<(NPIX/256)*(CC/256), 512, 0, stream>>>(
        xs1, kT1, dg1, noise1, B1sw, B1sb, B1bw, B1bb, bias1, s2, xs2);
    conv_gemm2<<<(NPIX/256)*(CC/256), 512, 0, stream>>>(
        xs2, kT2, dg2, noise2, B2sw, B2sb, B2bw, B2bb, bias2, outx, rgbw, outrgb);
}

// Round 12
// 318.138 us; speedup vs baseline: 1.1292x; 1.0175x over previous
//
#include <hip/hip_runtime.h>
#include <hip/hip_bf16.h>

#define BB 8
#define CC 512
#define HO 64
#define HP 66
#define NPIX (BB*HO*HO)   // 32768

typedef float f32x4 __attribute__((ext_vector_type(4)));
typedef __bf16 bf16x8 __attribute__((ext_vector_type(8)));
using bf16 = __hip_bfloat16;

__device__ __forceinline__ void gload16(const void* g, void* l) {
    __builtin_amdgcn_global_load_lds((const __attribute__((address_space(1))) void*)g,
                                     (__attribute__((address_space(3))) void*)l, 16, 0, 0);
}

__device__ __forceinline__ float waveRedSum(float v) {
    #pragma unroll
    for (int off = 32; off; off >>= 1) v += __shfl_down(v, off);
    return v;
}

// ---------------------------------------------------------------------------
// init_all: one launch, three independent jobs branch on blockIdx:
//  [0,2048)     prep_weights conv1/conv2; [2048,3088) halo zero xs1/xs2;
//  [3088,3184)  outrgb init with rgbb[c].
// ---------------------------------------------------------------------------
__global__ void init_all(const float* __restrict__ W1, const float* __restrict__ W2,
                         float* __restrict__ S21, float* __restrict__ S22,
                         bf16* __restrict__ kT1, bf16* __restrict__ kT2, float he,
                         bf16* __restrict__ xs1, bf16* __restrict__ xs2,
                         const float* __restrict__ rgbb, float* __restrict__ outrgb) {
    int blk = blockIdx.x, tid = threadIdx.x;
    if (blk < 2048) {
        int which = blk >> 10;
        const float* Wsrc = which ? W2 : W1;
        float* S2ho = which ? S22 : S21;
        bf16* keffT = which ? kT2 : kT1;
        int t = ((blk & 1023) << 8) + tid;
        int i = t & (CC-1), o = t >> 9;
        const float* wp = Wsrc + (i*CC + o)*9;
        float v[9]; float s2 = 0.f;
        #pragma unroll
        for (int k = 0; k < 9; ++k) { v[k] = wp[k] * he; s2 += v[k]*v[k]; }
        S2ho[o*CC + i] = s2;
        #pragma unroll
        for (int tp = 0; tp < 9; ++tp) keffT[(tp*CC + o)*CC + i] = (bf16)v[8 - tp];
    } else if (blk < 3088) {
        int sub = ((blk - 2048) << 2) + (tid >> 6);   // 0..4159
        int ln = tid & 63;
        bf16* dst = (sub & 1) ? xs2 : xs1;
        int idx = sub >> 1;                 // 0..2079
        int b = idx / 260, rm = idx - b*260;
        int p, q;
        if (rm < 66)       { p = 0;        q = rm; }
        else if (rm < 132) { p = 65;       q = rm - 66; }
        else if (rm < 196) { p = rm - 131; q = 0; }
        else               { p = rm - 195; q = 65; }
        f32x4* d4 = (f32x4*)(dst + ((size_t)((b*HP + p)*HP + q)) * CC);
        d4[ln] = f32x4{0.f, 0.f, 0.f, 0.f};
    } else {
        int t2 = ((blk - 3088) << 2) + (tid >> 6);    // 0..383
        int plane = t2 >> 4;                          // 0..23
        int c = plane - (plane/3)*3;
        float v = rgbb[c];
        *(f32x4*)(outrgb + (plane << 12) + ((t2 & 15) << 8) + ((tid & 63) << 2)) =
            f32x4{v, v, v, v};
    }
}

// one wave per (set, b, i): style[b,i] = sum_d w[b,d]*A[i,d]/sqrt(512) + Ab[i]
__global__ void style_kernel(const float* __restrict__ w,
                             const float* __restrict__ A1, const float* __restrict__ A1b,
                             const float* __restrict__ A2, const float* __restrict__ A2b,
                             float* __restrict__ s1, float* __restrict__ s2) {
    int wid = (blockIdx.x * blockDim.x + threadIdx.x) >> 6;
    int lane = threadIdx.x & 63;
    int set = wid >= BB*CC; int rem = set ? wid - BB*CC : wid;
    int b = rem >> 9, i = rem & (CC-1);
    const float* A = set ? A2 : A1;
    const float* wb = w + b*CC;
    float sum = 0.f;
    for (int d = lane; d < CC; d += 64) sum += wb[d] * A[i*CC + d];
    sum = waveRedSum(sum);
    if (lane == 0) {
        float r = sum * 0.04419417382415922f + (set ? A2b : A1b)[i];
        (set ? s2 : s1)[b*CC + i] = r;
    }
}

// one wave per (set, b, o): dg = gain * rsqrt(sum_i style^2 * S2ho[o][i] + eps)
__global__ void demod_kernel(const float* __restrict__ s1, const float* __restrict__ S21,
                             const float* __restrict__ s2, const float* __restrict__ S22,
                             float* __restrict__ dg1, float* __restrict__ dg2, float gain) {
    int wid = (blockIdx.x * blockDim.x + threadIdx.x) >> 6;
    int lane = threadIdx.x & 63;
    int set = wid >= BB*CC; int rem = set ? wid - BB*CC : wid;
    int b = rem >> 9, o = rem & (CC-1);
    const float* st = (set ? s2 : s1) + b*CC;
    const float* S2 = (set ? S22 : S21) + o*CC;
    float sum = 0.f;
    for (int i = lane; i < CC; i += 64) { float sv = st[i]; sum += sv*sv*S2[i]; }
    sum = waveRedSum(sum);
    if (lane == 0) (set ? dg2 : dg1)[b*CC + o] = gain * rsqrtf(sum + 1e-8f);
}

// block = (b, p): one full output row, 512 threads = channels.
// H-lerp hoisted into usl[32][CC]; q-loop unrolled -> static ds_read offsets.
__global__ void upsample_mod(const float* __restrict__ x, const float* __restrict__ s1,
                             bf16* __restrict__ xs1) {
    __shared__ float usl[32][CC];
    int blk = blockIdx.x;                  // b*64 + p
    int i = threadIdx.x;
    int b = blk >> 6, p = blk & 63;
    const float scale = 31.0f / 63.0f;
    float chf = p * scale; int h0 = (int)chf; float fh = chf - h0; int h1 = min(h0 + 1, 31);
    const float* xb = x + ((size_t)(b*CC + i) << 10);
    #pragma unroll
    for (int k = 0; k < 8; ++k) {
        f32x4 r0 = *(const f32x4*)(xb + (h0 << 5) + (k << 2));
        f32x4 r1 = *(const f32x4*)(xb + (h1 << 5) + (k << 2));
        #pragma unroll
        for (int e = 0; e < 4; ++e)
            usl[(k << 2) + e][i] = r0[e]*(1.f - fh) + r1[e]*fh;
    }
    float sv = s1[b*CC + i];
    bf16* op = xs1 + ((size_t)((b*HP + p + 1)*HP + 1))*CC + i;
    #pragma unroll
    for (int q = 0; q < 64; ++q) {
        float cwf = q * scale; int w0 = (int)cwf; float fw = cwf - w0;
        int w1 = min(w0 + 1, 31);
        float v = (usl[w0][i]*(1.f - fw) + usl[w1][i]*fw) * sv;
        op[q*CC] = (bf16)v;
    }
}

// ---------------------------------------------------------------------------
// Implicit-GEMM 3x3 conv. BM=BN=256, BK=64, 512 thr = 8 waves (2Mx4N),
// per-wave 128x64, 16x16x32 MFMA, XOR slot-swizzle (verified 0 conflicts).
// ROUND-12 CHANGE: intra-K-step barriers REMOVED (they were semantically
// unneeded — cur-buffer staged before step-entry barrier; staging writes nxt,
// read next step). Lockstep barriers forced SUM(LDS-port 2300cyc, MFMA
// 2480cyc) = measured 5200 cyc/step; free-running waves let one wave's
// ds_reads overlap another's MFMAs (m114 mechanism) -> target max() ~3200.
// Ledger: one vmcnt(0)+s_barrier per K-step (drains the 8 staging loads
// issued at step start, guards dbuf swap). Compiler schedules lgkmcnt.
// ---------------------------------------------------------------------------
#define SB  __builtin_amdgcn_sched_barrier(0)
#define BAR __builtin_amdgcn_s_barrier()
#define VMC(n)  asm volatile("s_waitcnt vmcnt(" #n ")" ::: "memory")

#define STAGE_A(d, h, U) do { \
    gload16((U) + aThr + (h)*(HP*1024),                 ldsA + (d)*32768 + (h)*16384); \
    gload16((U) + aThr + (h)*(HP*1024) + 2*(HP*1024),   ldsA + (d)*32768 + (h)*16384 + 8192); \
} while (0)

#define STAGE_B(d, h, U) do { \
    gload16((U) + bThr + (h)*32768,                     ldsB + (d)*32768 + (h)*16384); \
    gload16((U) + bThr + (h)*32768 + 131072,            ldsB + (d)*32768 + (h)*16384 + 8192); \
} while (0)

#define LOAD_A(d, fh) do { \
    _Pragma("unroll") \
    for (int fmq = 0; fmq < 4; ++fmq) { \
        afr[fmq][0] = *(const bf16x8*)(aRd + (d)*32768 + (fh)*16384 + fmq*2048 + swz0); \
        afr[fmq][1] = *(const bf16x8*)(aRd + (d)*32768 + (fh)*16384 + fmq*2048 + swz1); \
    } } while (0)

#define LOAD_B(d, nh) do { \
    _Pragma("unroll") \
    for (int fnq = 0; fnq < 2; ++fnq) { \
        bfr[nh][fnq][0] = *(const bf16x8*)(bRd + (d)*32768 + (nh)*16384 + fnq*2048 + swz0); \
        bfr[nh][fnq][1] = *(const bf16x8*)(bRd + (d)*32768 + (nh)*16384 + fnq*2048 + swz1); \
    } } while (0)

#define QUAD(fh, nh) do { \
    __builtin_amdgcn_s_setprio(1); \
    _Pragma("unroll") \
    for (int kc = 0; kc < 2; ++kc) \
    { _Pragma("unroll") \
      for (int fmq = 0; fmq < 4; ++fmq) \
      { _Pragma("unroll") \
        for (int fnq = 0; fnq < 2; ++fnq) \
            acc[(fh)*4+fmq][(nh)*2+fnq] = __builtin_amdgcn_mfma_f32_16x16x32_bf16( \
                afr[fmq][kc], bfr[nh][fnq][kc], acc[(fh)*4+fmq][(nh)*2+fnq], 0, 0, 0); } } \
    __builtin_amdgcn_s_setprio(0); } while (0)

// one K-step, barrier-free inside. cur/nxt: dbuf indices (compile-time).
// Stage all of step s+1 up-front (max flight), then reads+MFMAs in quadrant
// order (compiler inserts fine-grained lgkmcnt); one vmcnt+barrier at end.
#define KSTEP(cur, nxt, aN, bN, doStage) do { \
    if (doStage) { \
        STAGE_A(nxt, 0, aN); STAGE_A(nxt, 1, aN); \
        STAGE_B(nxt, 0, bN); STAGE_B(nxt, 1, bN); \
    } \
    LOAD_A(cur, 0); LOAD_B(cur, 0); \
    QUAD(0, 0); \
    LOAD_B(cur, 1); \
    QUAD(0, 1); \
    LOAD_A(cur, 1); \
    QUAD(1, 1); \
    QUAD(1, 0); \
    VMC(0); SB; BAR; SB; \
} while (0)

// shared preamble + K-loop (expands inside each kernel body)
#define CONV_COMMON \
    __shared__ __attribute__((aligned(16))) bf16 As[32768]; \
    __shared__ __attribute__((aligned(16))) bf16 Bs[32768]; \
    const int tid = threadIdx.x; \
    const int wave = tid >> 6, lane = tid & 63; \
    const int tileId = ((blockIdx.x & 7) << 5) + (blockIdx.x >> 3); \
    const int mtile = tileId >> 1, ntile = tileId & 1; \
    const int m0 = mtile << 8, n0 = ntile << 8; \
    const int b  = m0 >> 12; \
    const int p0 = (m0 & 4095) >> 6; \
    const int wm = wave >> 2, wn = wave & 3; \
    const int l15 = lane & 15; \
    const int srcSwz = (((tid & 7) ^ ((tid >> 3) & 7)) << 4); \
    const int aThr = ((tid >> 3) << 10) + srcSwz; \
    const int bThr = (((tid >> 8) & 1) << 16) + (((tid >> 3) & 31) << 10) + srcSwz; \
    char* const ldsA = (char*)As + tid*16; \
    char* const ldsB = (char*)Bs + tid*16; \
    const char* const aRd = (const char*)As + (((wm << 6) + l15) << 7); \
    const char* const bRd = (const char*)Bs + (((wn << 5) + l15) << 7); \
    const int swz0 = (((lane >> 4)    ) ^ (lane & 7)) << 4; \
    const int swz1 = (((lane >> 4) | 4) ^ (lane & 7)) << 4; \
    f32x4 acc[8][4]; \
    _Pragma("unroll") \
    for (int i_ = 0; i_ < 8; ++i_) \
        _Pragma("unroll") \
        for (int j_ = 0; j_ < 4; ++j_) acc[i_][j_] = f32x4{0.f, 0.f, 0.f, 0.f}; \
    bf16x8 afr[4][2], bfr[2][2][2]; \
    auto abase = [&](int st) -> const char* { \
        int t = st >> 3; int dh = (t*11) >> 5; int dw = t - dh*3; \
        return (const char*)xs + ((size_t)((b*HP + p0 + dh)*HP + dw) << 10) + ((st & 7) << 7); \
    }; \
    auto bbase = [&](int st) -> const char* { \
        int t = st >> 3; \
        return (const char*)keffT + ((size_t)(t*CC + n0) << 10) + ((st & 7) << 7); \
    }; \
    { \
        const char* a0 = abase(0); const char* b0 = bbase(0); \
        STAGE_A(0, 0, a0); STAGE_A(0, 1, a0); \
        STAGE_B(0, 0, b0); STAGE_B(0, 1, b0); \
        VMC(0); SB; BAR; SB; \
    } \
    _Pragma("unroll 1") \
    for (int it = 0; it < 36; ++it) { \
        const bool more = (it < 35); \
        const char* aE = abase(2*it + 1); const char* bE = bbase(2*it + 1); \
        const char* aO = abase(2*it + 2); const char* bO = bbase(2*it + 2); \
        KSTEP(0, 1, aE, bE, true); \
        KSTEP(1, 0, aO, bO, more); \
    }

// conv1: writes bf16 padded-NHWC xs2 (pre-multiplied by next style).
__global__ __launch_bounds__(512, 2) void conv_gemm1(
    const bf16* __restrict__ xs, const bf16* __restrict__ keffT,
    const float* __restrict__ dg, const float* __restrict__ noise,
    const float* __restrict__ nsw, const float* __restrict__ nsb,
    const float* __restrict__ nbw, const float* __restrict__ nbb,
    const float* __restrict__ biasv, const float* __restrict__ stnext,
    bf16* __restrict__ outb) {
    CONV_COMMON
    // epilogue: px = m0+wm*128+fm*16+(lane>>4)*4+r; ch = n0+wn*64+fn*16+l15
    const float* dgb = dg + b*CC;
    int nIdx[4]; float pdg[4], pnsw[4], pnsb[4], pnbw[4], pnbb[4], pbias[4], pst[4];
    #pragma unroll
    for (int fn = 0; fn < 4; ++fn) {
        int n = n0 + (wn << 6) + (fn << 4) + l15;
        nIdx[fn] = n;
        pdg[fn] = dgb[n]; pnsw[fn] = nsw[n]; pnsb[fn] = nsb[n];
        pnbw[fn] = nbw[n]; pnbb[fn] = nbb[n]; pbias[fn] = biasv[n];
        pst[fn] = stnext[b*CC + n];
    }
    #pragma unroll
    for (int fm = 0; fm < 8; ++fm) {
        const int mbase = m0 + (wm << 7) + (fm << 4) + ((lane >> 4) << 2);
        const f32x4 nsv = *(const f32x4*)(noise + mbase);
        #pragma unroll
        for (int r = 0; r < 4; ++r) {
            int mloc = mbase + r;
            float ns = nsv[r];
            int prow = (mloc & 4095) >> 6, qcol = mloc & 63;
            #pragma unroll
            for (int fn = 0; fn < 4; ++fn) {
                float v = acc[fm][fn][r] * pdg[fn];
                v = v * (ns*pnsw[fn] + pnsb[fn]) + (ns*pnbw[fn] + pnbb[fn]) + pbias[fn];
                v = fmaxf(v, 0.2f*v);   // leaky relu 0.2
                outb[(((b*HP) + prow + 1)*HP + (qcol + 1))*CC + nIdx[fn]] =
                    (bf16)(v * pst[fn]);
            }
        }
    }
}

// conv2: writes f32 NCHW outx + fused rgb (atomics spread over lanes 0..2).
__global__ __launch_bounds__(512, 2) void conv_gemm2(
    const bf16* __restrict__ xs, const bf16* __restrict__ keffT,
    const float* __restrict__ dg, const float* __restrict__ noise,
    const float* __restrict__ nsw, const float* __restrict__ nsb,
    const float* __restrict__ nbw, const float* __restrict__ nbb,
    const float* __restrict__ biasv, float* __restrict__ outf,
    const float* __restrict__ rgbwv, float* __restrict__ outrgb) {
    CONV_COMMON
    const float* dgb = dg + b*CC;
    int nIdx[4]; float pdg[4], pnsw[4], pnsb[4], pnbw[4], pnbb[4], pbias[4];
    float w0[4], w1[4], w2[4];
    const float heR = 0.03f * 0.04419417382415922f;
    #pragma unroll
    for (int fn = 0; fn < 4; ++fn) {
        int n = n0 + (wn << 6) + (fn << 4) + l15;
        nIdx[fn] = n;
        pdg[fn] = dgb[n]; pnsw[fn] = nsw[n]; pnsb[fn] = nsb[n];
        pnbw[fn] = nbw[n]; pnbb[fn] = nbb[n]; pbias[fn] = biasv[n];
        w0[fn] = rgbwv[n] * heR;
        w1[fn] = rgbwv[CC + n] * heR;
        w2[fn] = rgbwv[2*CC + n] * heR;
    }
    #pragma unroll
    for (int fm = 0; fm < 8; ++fm) {
        const int mbase = m0 + (wm << 7) + (fm << 4) + ((lane >> 4) << 2);
        const f32x4 nsv = *(const f32x4*)(noise + mbase);
        f32x4 pc0 = {0.f,0.f,0.f,0.f}, pc1 = {0.f,0.f,0.f,0.f}, pc2 = {0.f,0.f,0.f,0.f};
        #pragma unroll
        for (int fn = 0; fn < 4; ++fn) {
            f32x4 vv;
            #pragma unroll
            for (int r = 0; r < 4; ++r) {
                float ns = nsv[r];
                float v = acc[fm][fn][r] * pdg[fn];
                v = v * (ns*pnsw[fn] + pnsb[fn]) + (ns*pnbw[fn] + pnbb[fn]) + pbias[fn];
                vv[r] = fmaxf(v, 0.2f*v);
            }
            pc0 += vv * w0[fn]; pc1 += vv * w1[fn]; pc2 += vv * w2[fn];
            *(f32x4*)(outf + ((size_t)(b*CC + nIdx[fn]) << 12) + (mbase & 4095)) = vv;
        }
        // rgb partial: butterfly over the 16 l15 lanes -> all lanes hold sums;
        // lanes 0..2 each issue one atomic.
        #pragma unroll
        for (int r = 0; r < 4; ++r) {
            float a0 = pc0[r], a1 = pc1[r], a2 = pc2[r];
            #pragma unroll
            for (int mk = 1; mk < 16; mk <<= 1) {
                a0 += __shfl_xor(a0, mk);
                a1 += __shfl_xor(a1, mk);
                a2 += __shfl_xor(a2, mk);
            }
            if (l15 < 3) {
                float av = (l15 == 0) ? a0 : (l15 == 1) ? a1 : a2;
                int px = (mbase + r) & 4095;
                atomicAdd(outrgb + (b*3 + l15)*4096 + px, av);
            }
        }
    }
}

extern "C" void kernel_launch(void* const* d_in, const int* in_sizes, int n_in,
                              void* d_out, int out_size, void* d_ws, size_t ws_size,
                              hipStream_t stream) {
    const float* x      = (const float*)d_in[0];
    const float* w      = (const float*)d_in[1];
    const float* noise1 = (const float*)d_in[2];
    const float* noise2 = (const float*)d_in[3];
    const float* conv1w = (const float*)d_in[4];
    const float* bias1  = (const float*)d_in[5];
    const float* conv2w = (const float*)d_in[6];
    const float* bias2  = (const float*)d_in[7];
    const float* A1w = (const float*)d_in[8];
    const float* A1b = (const float*)d_in[9];
    const float* A2w = (const float*)d_in[10];
    const float* A2b = (const float*)d_in[11];
    const float* B1sw = (const float*)d_in[12];
    const float* B1sb = (const float*)d_in[13];
    const float* B1bw = (const float*)d_in[14];
    const float* B1bb = (const float*)d_in[15];
    const float* B2sw = (const float*)d_in[16];
    const float* B2sb = (const float*)d_in[17];
    const float* B2bw = (const float*)d_in[18];
    const float* B2bb = (const float*)d_in[19];
    const float* rgbw = (const float*)d_in[20];
    const float* rgbb = (const float*)d_in[21];

    char* ws = (char*)d_ws;
    size_t off = 0;
    auto alloc = [&](size_t bytes) { char* p = ws + off; off += (bytes + 255) & ~(size_t)255; return p; };
    const size_t xsBytes = (size_t)BB*HP*HP*CC*2;
    bf16* xs1 = (bf16*)alloc(xsBytes);
    bf16* xs2 = (bf16*)alloc(xsBytes);
    bf16* kT1 = (bf16*)alloc((size_t)9*CC*CC*2);
    bf16* kT2 = (bf16*)alloc((size_t)9*CC*CC*2);
    float* S21 = (float*)alloc((size_t)CC*CC*4);
    float* S22 = (float*)alloc((size_t)CC*CC*4);
    float* s1  = (float*)alloc(BB*CC*4);
    float* s2  = (float*)alloc(BB*CC*4);
    float* dg1 = (float*)alloc(BB*CC*4);
    float* dg2 = (float*)alloc(BB*CC*4);

    float* outx   = (float*)d_out;
    float* outrgb = outx + (size_t)BB*CC*HO*HO;

    const float gain = 1.41421356237309515f;
    const float he = gain / sqrtf(512.f * 9.f);
    init_all<<<3184, 256, 0, stream>>>(conv1w, conv2w, S21, S22, kT1, kT2, he,
                                       xs1, xs2, rgbb, outrgb);
    style_kernel<<<2*BB*CC/4, 256, 0, stream>>>(w, A1w, A1b, A2w, A2b, s1, s2);
    demod_kernel<<<2*BB*CC/4, 256, 0, stream>>>(s1, S21, s2, S22, dg1, dg2, gain);
    upsample_mod<<<BB*HO, CC, 0, stream>>>(x, s1, xs1);
    conv_gemm1<<<(NPIX/256)*(CC/256), 512, 0, stream>>>(
        xs1, kT1, dg1, noise1, B1sw, B1sb, B1bw, B1bb, bias1, s2, xs2);
    conv_gemm2<<<(NPIX/256)*(CC/256), 512, 0, stream>>>(
        xs2, kT2, dg2, noise2, B2sw, B2sb, B2bw, B2bb, bias2, outx, rgbw, outrgb);
}